// Round 13
// baseline (467.380 us; speedup 1.0000x reference)
//
#include <hip/hip_runtime.h>
#include <cstdint>
#include <cstddef>

typedef unsigned long long u64;
typedef unsigned int u32;
typedef unsigned short ushort_t;
typedef __attribute__((ext_vector_type(8))) short s8v;
typedef __attribute__((ext_vector_type(4))) float f4v;

#define NMS_THR 0.5f
#define SCORE_THR 0.05f
#define CLAMPV 4.135166556742356f
#define MFMA16(a,b,c) __builtin_amdgcn_mfma_f32_16x16x32_bf16(a,b,c,0,0,0)

static __device__ inline ushort_t f2b(float f) {
    u32 u = __float_as_uint(f);
    return (ushort_t)((u + 0x7FFFu + ((u >> 16) & 1u)) >> 16);
}
static __device__ inline float b2f(ushort_t h) {
    return __uint_as_float((u32)h << 16);
}
static __device__ inline u64 shfl64(u64 v, int src) {
    int lo = __shfl((int)(u32)v, src, 64);
    int hi = __shfl((int)(u32)(v >> 32), src, 64);
    return ((u64)(u32)hi << 32) | (u64)(u32)lo;
}
// direct global->LDS DMA, 16B per lane. LDS dest is wave-uniform base + lane*16.
static __device__ __forceinline__ void gload16(const void* g, void* l) {
    __builtin_amdgcn_global_load_lds(
        (const __attribute__((address_space(1))) void*)g,
        (__attribute__((address_space(3))) void*)l, 16, 0, 0);
}

// ---------------- transpose (rows, cols) -> (cols, rows) ----------------
__global__ __launch_bounds__(256) void transpose_k(const float* __restrict__ in,
        float* __restrict__ out, int rows, int cols) {
    __shared__ float tile[32][33];
    int c0 = blockIdx.x * 32, r0 = blockIdx.y * 32;
    int tx = threadIdx.x, ty = threadIdx.y;
#pragma unroll
    for (int i = 0; i < 32; i += 8) {
        int r = r0 + ty + i, c = c0 + tx;
        if (r < rows && c < cols) tile[ty + i][tx] = in[(size_t)r * cols + c];
    }
    __syncthreads();
#pragma unroll
    for (int i = 0; i < 32; i += 8) {
        int r = c0 + ty + i, c = r0 + tx;
        if (r < cols && c < rows) out[(size_t)r * rows + c] = tile[tx][ty + i];
    }
}

// ---------------- weight converts ----------------
// fc1 weight in K-BLOCKED layout: [panel p=o>>7][kstep=k'>>5][row=o&127][32].
__global__ __launch_bounds__(256) void cvt_w1_k(const float* __restrict__ w,
        ushort_t* __restrict__ Wh, ushort_t* __restrict__ Wl) {
    __shared__ float row[12544];
    int o = blockIdx.x;
    const float* src = w + (size_t)o * 12544;
    for (int i = threadIdx.x; i < 12544; i += 256) row[i] = src[i];
    __syncthreads();
    int p = o >> 7, r = o & 127;
    for (int i = threadIdx.x; i < 12544; i += 256) {
        int s = i >> 8, c = i & 255;
        float v = row[c * 49 + s];
        ushort_t h = f2b(v);
        ushort_t l = f2b(v - b2f(h));
        size_t idx = ((size_t)(p * 392 + (i >> 5)) << 12) + (r << 5) + (i & 31);
        Wh[idx] = h;
        Wl[idx] = l;
    }
}

// fused hi/lo split for fc2 (1048576) + cls (82944) + reg (331776)
__global__ __launch_bounds__(256) void cvt_hilo3_k(const float* __restrict__ w2,
        const float* __restrict__ wc, const float* __restrict__ wr,
        ushort_t* __restrict__ h2, ushort_t* __restrict__ l2,
        ushort_t* __restrict__ hc, ushort_t* __restrict__ lc,
        ushort_t* __restrict__ hr, ushort_t* __restrict__ lr) {
    int i = blockIdx.x * 256 + threadIdx.x;
    const float* w; ushort_t* h; ushort_t* l; int r;
    if (i < 1048576) { w = w2; h = h2; l = l2; r = i; }
    else if (i < 1131520) { w = wc; h = hc; l = lc; r = i - 1048576; }
    else if (i < 1463296) { w = wr; h = hr; l = lr; r = i - 1131520; }
    else return;
    float v = w[r];
    ushort_t hh = f2b(v);
    h[r] = hh;
    l[r] = f2b(v - b2f(hh));
}

// fused conv weights (4 x 589824) + deconv (262144) convert; also zeroes CNT
__global__ __launch_bounds__(256) void cvt_allw_k(const float* __restrict__ w1,
        const float* __restrict__ w2, const float* __restrict__ w3,
        const float* __restrict__ w4, const float* __restrict__ wd,
        ushort_t* __restrict__ o1, ushort_t* __restrict__ o2,
        ushort_t* __restrict__ o3, ushort_t* __restrict__ o4,
        ushort_t* __restrict__ od, int* __restrict__ cnt) {
    int t = blockIdx.x * 256 + threadIdx.x;
    if (t == 0) *cnt = 0;
    if (t < 2359296) {
        int which = t / 589824;
        int r = t - which * 589824;
        const float* w = (which == 0) ? w1 : (which == 1) ? w2 : (which == 2) ? w3 : w4;
        ushort_t* o = (which == 0) ? o1 : (which == 1) ? o2 : (which == 2) ? o3 : o4;
        int oc = r / 2304;
        int rem = r - oc * 2304;
        int kk = rem >> 8;
        int ci = rem & 255;
        o[r] = f2b(w[oc * 2304 + ci * 9 + kk]);
    } else {
        int r = t - 2359296;
        if (r < 262144) {
            int m = r >> 8;
            int ci = r & 255;
            od[r] = f2b(wd[ci * 1024 + m]);
        }
    }
}

// ---------------- roi align (FC path): hi/lo bf16 out, K-blocked layout ----------------
__global__ __launch_bounds__(256) void roi_align_hilo_k(const float* __restrict__ feat,
        const float* __restrict__ rois, ushort_t* __restrict__ outh,
        ushort_t* __restrict__ outl) {
    int c = threadIdx.x;
    int s = blockIdx.x;
    int n = blockIdx.y;
    const int P = 7;
    int py = s / P, px = s - py * P;
    float rx1 = rois[n * 4 + 0] * 0.25f;
    float ry1 = rois[n * 4 + 1] * 0.25f;
    float rx2 = rois[n * 4 + 2] * 0.25f;
    float ry2 = rois[n * 4 + 3] * 0.25f;
    float bw = fmaxf(rx2 - rx1, 1.0f) / (float)P;
    float bh = fmaxf(ry2 - ry1, 1.0f) / (float)P;
    float acc = 0.0f;
#pragma unroll
    for (int sy = 0; sy < 2; sy++)
#pragma unroll
        for (int sx = 0; sx < 2; sx++) {
            float y = ry1 + ((float)py + ((float)sy + 0.5f) * 0.5f) * bh;
            float x = rx1 + ((float)px + ((float)sx + 0.5f) * 0.5f) * bw;
            y = fminf(fmaxf(y, 0.0f), 199.0f);
            x = fminf(fmaxf(x, 0.0f), 199.0f);
            float y0f = floorf(y), x0f = floorf(x);
            float ly = y - y0f, lx = x - x0f;
            int y0 = (int)y0f, x0 = (int)x0f;
            int y1 = min(y0 + 1, 199), x1 = min(x0 + 1, 199);
            float v00 = feat[((size_t)(y0 * 200 + x0)) * 256 + c];
            float v01 = feat[((size_t)(y0 * 200 + x1)) * 256 + c];
            float v10 = feat[((size_t)(y1 * 200 + x0)) * 256 + c];
            float v11 = feat[((size_t)(y1 * 200 + x1)) * 256 + c];
            acc += v00 * (1.0f - ly) * (1.0f - lx) + v01 * (1.0f - ly) * lx
                 + v10 * ly * (1.0f - lx) + v11 * ly * lx;
        }
    float v = acc * 0.25f;
    ushort_t h = f2b(v);
    int kp = s * 256 + c;                       // k' index
    size_t idx = ((size_t)((n >> 7) * 392 + (kp >> 5)) << 12)
               + ((n & 127) << 5) + (kp & 31);
    outh[idx] = h;
    outl[idx] = f2b(v - b2f(h));
}

// ---------------- roi align (mask path), bf16 channels-last out ----------------
__global__ __launch_bounds__(256) void roi_align_mask_k(const float* __restrict__ feat,
        const float* __restrict__ dets, ushort_t* __restrict__ out) {
    int c = threadIdx.x;
    int s = blockIdx.x;
    int n = blockIdx.y;
    const int P = 14;
    int py = s / P, px = s - py * P;
    float rx1 = dets[n * 4 + 0] * 0.25f;
    float ry1 = dets[n * 4 + 1] * 0.25f;
    float rx2 = dets[n * 4 + 2] * 0.25f;
    float ry2 = dets[n * 4 + 3] * 0.25f;
    float bw = fmaxf(rx2 - rx1, 1.0f) / (float)P;
    float bh = fmaxf(ry2 - ry1, 1.0f) / (float)P;
    float acc = 0.0f;
#pragma unroll
    for (int sy = 0; sy < 2; sy++)
#pragma unroll
        for (int sx = 0; sx < 2; sx++) {
            float y = ry1 + ((float)py + ((float)sy + 0.5f) * 0.5f) * bh;
            float x = rx1 + ((float)px + ((float)sx + 0.5f) * 0.5f) * bw;
            y = fminf(fmaxf(y, 0.0f), 199.0f);
            x = fminf(fmaxf(x, 0.0f), 199.0f);
            float y0f = floorf(y), x0f = floorf(x);
            float ly = y - y0f, lx = x - x0f;
            int y0 = (int)y0f, x0 = (int)x0f;
            int y1 = min(y0 + 1, 199), x1 = min(x0 + 1, 199);
            float v00 = feat[((size_t)(y0 * 200 + x0)) * 256 + c];
            float v01 = feat[((size_t)(y0 * 200 + x1)) * 256 + c];
            float v10 = feat[((size_t)(y1 * 200 + x0)) * 256 + c];
            float v11 = feat[((size_t)(y1 * 200 + x1)) * 256 + c];
            acc += v00 * (1.0f - ly) * (1.0f - lx) + v01 * (1.0f - ly) * lx
                 + v10 * ly * (1.0f - lx) + v11 * ly * lx;
        }
    out[((size_t)n * 196 + s) * 256 + c] = f2b(acc * 0.25f);
}

// ---------------- error-compensated bf16 MFMA split-K GEMM (64-tile) ----------------
// (kept for fc2 / cls+reg; fc1 uses gemm128_k below)
__global__ __launch_bounds__(256) void gemm3_mfma_k(const ushort_t* __restrict__ Ah,
        const ushort_t* __restrict__ Al, const ushort_t* __restrict__ Bh,
        const ushort_t* __restrict__ Bl, float* __restrict__ P,
        int M, int N, int K, int kchunk) {
    __shared__ __align__(16) ushort_t AsH[2048], AsL[2048], BsH[2048], BsL[2048];
    int t = threadIdx.x;
    int wave = t >> 6, lane = t & 63;
    int wm = wave >> 1, wn = wave & 1;
    int m0 = blockIdx.y * 64, n0 = blockIdx.x * 64;
    int z = blockIdx.z;
    int kb = z * kchunk, ke = min(K, kb + kchunk);
    f4v acc[2][2] = {};
    int rl = lane & 15, kseg = lane >> 4;
    // source pre-swizzle: LDS granule t holds global granule t^((t>>3)&3)
    int gsw = t ^ ((t >> 3) & 3);
    int grow = gsw >> 2, gseg = gsw & 3;
    size_t aoff = (size_t)(m0 + grow) * K + gseg * 8;
    size_t boff = (size_t)(n0 + grow) * K + gseg * 8;
    for (int k0 = kb; k0 < ke; k0 += 32) {
        gload16(&Ah[aoff + k0], &AsH[t * 8]);
        gload16(&Al[aoff + k0], &AsL[t * 8]);
        gload16(&Bh[boff + k0], &BsH[t * 8]);
        gload16(&Bl[boff + k0], &BsL[t * 8]);
        __syncthreads();
        s8v ah[2], al[2], bh[2], bl[2];
#pragma unroll
        for (int i = 0; i < 2; i++) {
            int row = wm * 32 + i * 16 + rl;
            int idx = row * 32 + kseg * 8;
            idx ^= ((idx >> 6) & 3) << 3;
            ah[i] = *(const s8v*)&AsH[idx];
            al[i] = *(const s8v*)&AsL[idx];
        }
#pragma unroll
        for (int j = 0; j < 2; j++) {
            int col = wn * 32 + j * 16 + rl;
            int idx = col * 32 + kseg * 8;
            idx ^= ((idx >> 6) & 3) << 3;
            bh[j] = *(const s8v*)&BsH[idx];
            bl[j] = *(const s8v*)&BsL[idx];
        }
#pragma unroll
        for (int i = 0; i < 2; i++)
#pragma unroll
            for (int j = 0; j < 2; j++) {
                acc[i][j] = MFMA16(al[i], bh[j], acc[i][j]);
                acc[i][j] = MFMA16(ah[i], bl[j], acc[i][j]);
                acc[i][j] = MFMA16(ah[i], bh[j], acc[i][j]);
            }
        __syncthreads();
    }
    float* Pz = P + (size_t)z * M * N;
    int rq = lane >> 4;
#pragma unroll
    for (int i = 0; i < 2; i++) {
#pragma unroll
        for (int j = 0; j < 2; j++) {
            int col = n0 + wn * 32 + j * 16 + rl;
            if (col >= N) continue;
            int m = m0 + wm * 32 + i * 16 + rq * 4;
#pragma unroll
            for (int r = 0; r < 4; r++)
                Pz[(size_t)(m + r) * N + col] = acc[i][j][r];
        }
    }
}

// ---------------- 128x128-tile hi/lo GEMM for fc1, K-blocked operands ----------------
// R13: 3-buffer depth-2 pipeline with COUNTED vmcnt + raw s_barrier (T3/T4).
// R9-R12 established: __syncthreads forces vmcnt(0) -> prefetch depth capped
// at 1, leaving ~1.3k cyc/step of exposed L2/L3 latency. Now: iteration ks
// issues S(ks+2) into the buffer read at ks-1 (reads provably complete: its
// MFMAs consumed them before ks-1's barrier), computes S(ks), then waits
// vmcnt(4) -- the newest 4 loads stay in flight across the barrier. Every
// wave issues the identical 4-load pattern and waits its own oldest-4, so
// after the barrier the whole next tile is resident (m201's scheme). Math
// unchanged -> bitwise-identical. LDS 96KB (1 block/CU, same as before).
__global__ __launch_bounds__(512) void gemm128_k(const ushort_t* __restrict__ Ah,
        const ushort_t* __restrict__ Al, const ushort_t* __restrict__ Bh,
        const ushort_t* __restrict__ Bl, float* __restrict__ P,
        int M, int N, int nsteps_total, int chunk_steps) {
    __shared__ __align__(16) ushort_t AsH[3][4096], AsL[3][4096], BsH[3][4096], BsL[3][4096];
    int t = threadIdx.x;
    int wave = t >> 6, lane = t & 63;
    int wm = wave >> 2, wn = wave & 3;          // 2 x 4 wave grid, wave = 64x32
    // grid remap: launched as (z, x, y) so z is fastest -> z maps to XCD
    int z  = blockIdx.x;
    int xb = blockIdx.y;                        // N-block
    int yb = blockIdx.z;                        // M-block
    int sb = z * chunk_steps, se = min(nsteps_total, sb + chunk_steps);
    f4v acc[4][2] = {};
    int rl = lane & 15, kseg = lane >> 4;
    // source pre-swizzle: LDS granule t holds global granule t^((t>>3)&3)
    int gsw = t ^ ((t >> 3) & 3);
    size_t abase = ((size_t)yb * nsteps_total) << 12;
    size_t bbase = ((size_t)xb * nsteps_total) << 12;
    int goff = gsw * 8;
#define G128_ISSUE(KS, BUF) do { \
        size_t o_ = ((size_t)(KS) << 12) + goff; \
        gload16(&Ah[abase + o_], &AsH[BUF][t * 8]); \
        gload16(&Al[abase + o_], &AsL[BUF][t * 8]); \
        gload16(&Bh[bbase + o_], &BsH[BUF][t * 8]); \
        gload16(&Bl[bbase + o_], &BsL[BUF][t * 8]); \
    } while (0)
    // prologue: stage sb -> buf0, sb+1 -> buf1
    G128_ISSUE(sb, 0);
    bool have1 = (sb + 1 < se);
    if (have1) {
        G128_ISSUE(sb + 1, 1);
        asm volatile("s_waitcnt vmcnt(4)" ::: "memory");   // buf0 resident
    } else {
        asm volatile("s_waitcnt vmcnt(0)" ::: "memory");
    }
    __builtin_amdgcn_s_barrier();
    int cur = 0;
    for (int ks = sb; ks < se; ks++) {
        bool iss = (ks + 2 < se);
        if (iss) {
            int nb = cur + 2; if (nb >= 3) nb -= 3;
            G128_ISSUE(ks + 2, nb);
        }
        s8v ah[4], al[4], bh[2], bl[2];
#pragma unroll
        for (int i = 0; i < 4; i++) {
            int row = wm * 64 + i * 16 + rl;
            int idx = row * 32 + kseg * 8;
            idx ^= ((idx >> 6) & 3) << 3;
            ah[i] = *(const s8v*)&AsH[cur][idx];
            al[i] = *(const s8v*)&AsL[cur][idx];
        }
#pragma unroll
        for (int j = 0; j < 2; j++) {
            int col = wn * 32 + j * 16 + rl;
            int idx = col * 32 + kseg * 8;
            idx ^= ((idx >> 6) & 3) << 3;
            bh[j] = *(const s8v*)&BsH[cur][idx];
            bl[j] = *(const s8v*)&BsL[cur][idx];
        }
#pragma unroll
        for (int i = 0; i < 4; i++)
#pragma unroll
            for (int j = 0; j < 2; j++) {
                acc[i][j] = MFMA16(al[i], bh[j], acc[i][j]);
                acc[i][j] = MFMA16(ah[i], bl[j], acc[i][j]);
                acc[i][j] = MFMA16(ah[i], bh[j], acc[i][j]);
            }
        if (ks + 1 < se) {
            // wait for next buffer's 4 loads (oldest); keep the newest 4 flying
            if (iss) asm volatile("s_waitcnt vmcnt(4)" ::: "memory");
            else     asm volatile("s_waitcnt vmcnt(0)" ::: "memory");
            __builtin_amdgcn_s_barrier();
        }
        cur = cur + 1; if (cur >= 3) cur = 0;
    }
#undef G128_ISSUE
    float* Pz = P + (size_t)z * M * N;
    int rq = lane >> 4;
    int m0 = yb * 128, n0 = xb * 128;
#pragma unroll
    for (int i = 0; i < 4; i++) {
#pragma unroll
        for (int j = 0; j < 2; j++) {
            int col = n0 + wn * 32 + j * 16 + rl;
            if (col >= N) continue;
            int m = m0 + wm * 64 + i * 16 + rq * 4;
#pragma unroll
            for (int r = 0; r < 4; r++)
                Pz[(size_t)(m + r) * N + col] = acc[i][j][r];
        }
    }
}

// reduce split-K partials + bias (+relu); write f32 and/or hi+lo bf16
__global__ __launch_bounds__(256) void reduce2_k(const float* __restrict__ P,
        const float* __restrict__ bias, float* __restrict__ Cf,
        ushort_t* __restrict__ Ch, ushort_t* __restrict__ Cl,
        int M, int N, int nsplit, int relu) {
    int idx = blockIdx.x * 256 + threadIdx.x;
    if (idx >= M * N) return;
    int n = idx % N;
    float s = 0.0f;
    for (int z = 0; z < nsplit; z++) s += P[(size_t)z * M * N + idx];
    s += bias[n];
    if (relu) s = fmaxf(s, 0.0f);
    if (Cf) Cf[idx] = s;
    if (Ch) {
        ushort_t h = f2b(s);
        Ch[idx] = h;
        Cl[idx] = f2b(s - b2f(h));
    }
}

// reduce for merged cls+reg GEMM (M=512, N=405)
__global__ __launch_bounds__(256) void reduce_cr_k(const float* __restrict__ P,
        const float* __restrict__ cls_b, const float* __restrict__ reg_b,
        float* __restrict__ LOGI, float* __restrict__ REG) {
    int idx = blockIdx.x * 256 + threadIdx.x;
    if (idx >= 512 * 405) return;
    int n = idx / 405, col = idx - n * 405;
    float s = 0.0f;
    for (int z = 0; z < 8; z++) s += P[(size_t)z * 512 * 405 + idx];
    if (col < 81) LOGI[n * 81 + col] = s + cls_b[col];
    else REG[n * 324 + (col - 81)] = s + reg_b[col - 81];
}

// ---------------- roi-resident bf16 MFMA 3x3 conv, LDS weights + global_load_lds ----------------
// R12 structure: zero-pixel sentinel (halo cndmask deleted); R8 paired
// cs-stages (K=64/stage, 36 barriers).
__global__ __launch_bounds__(256) void conv3_roi_k(const ushort_t* __restrict__ Wb,
        const ushort_t* __restrict__ In, const float* __restrict__ bias,
        ushort_t* __restrict__ Out) {
    __shared__ __align__(16) ushort_t Ibuf[200 * 128];
    __shared__ __align__(16) ushort_t Ws[2][4096];   // [buf][cs-parity*2048 + idx]
    int bid = blockIdx.x;
    int roiLow = bid & 7;
    int q = bid >> 3;
    int slice = q & 3;
    int roi = (q >> 2) * 8 + roiLow;
    if (roi >= 100) return;
    int t = threadIdx.x;
    int wave = t >> 6, lane = t & 63;
    int rl = lane & 15, kseg = lane >> 4;
    int m0 = slice * 64;
    f4v acc[4][4] = {};
    int yb[4], xb[4];
    bool cok[4];
#pragma unroll
    for (int j = 0; j < 4; j++) {
        int col = (j * 4 + wave) * 16 + rl;
        cok[j] = col < 196;
        int cc = cok[j] ? col : 0;
        yb[j] = cc / 14;
        xb[j] = cc - yb[j] * 14;
    }
    // zero sentinel pixel row 196 (persists across halves; staging only
    // writes pixels 0..195). 16 threads x 8 ushorts = 128.
    if (t < 16) {
        s8v zz = {0, 0, 0, 0, 0, 0, 0, 0};
        *(s8v*)&Ibuf[196 * 128 + t * 8] = zz;
    }
    // weight staging: LDS granule t holds global granule t^((t>>3)&3)
    int gsw = t ^ ((t >> 3) & 3);
    const ushort_t* gsrc = Wb + (size_t)(m0 + (gsw >> 2)) * 2304 + (gsw & 3) * 8;
    int cur = 0;
    for (int half = 0; half < 2; half++) {
        // Ibuf staging: granule (pix,u) sources (pix, u^(pix&7)) — linear dest
        for (int uidx = t; uidx < 3136; uidx += 256) {
            int pix = uidx >> 4, u = uidx & 15;
            int usw = u ^ (pix & 7);
            gload16(&In[(size_t)(roi * 196 + pix) * 256 + half * 128 + usw * 8],
                    &Ibuf[uidx * 8]);
        }
        if (half == 0) {  // prologue: stage (kk=0, p=0) pair into Ws[0]
            gload16(&gsrc[0], &Ws[0][t * 8]);
            gload16(&gsrc[32], &Ws[0][2048 + t * 8]);
        }
        __syncthreads();
        for (int kk = 0; kk < 9; kk++) {
            int ky = kk / 3, kx = kk - ky * 3;
            int spix[4];
#pragma unroll
            for (int j = 0; j < 4; j++) {
                int iy = yb[j] + ky - 1, ix = xb[j] + kx - 1;
                bool sval = cok[j] && iy >= 0 && iy < 14 && ix >= 0 && ix < 14;
                spix[j] = sval ? (iy * 14 + ix) : 196;   // 196 = zero sentinel
            }
#pragma unroll
            for (int p = 0; p < 2; p++) {
                int s = kk * 2 + p;               // stage index in [0,17]
                bool pf = (s < 17) || (half == 0);
                int nkbase;
                if (s < 17) {
                    int ns = s + 1;
                    nkbase = (ns >> 1) * 256 + half * 128 + (ns & 1) * 64;
                } else {
                    nkbase = 128;                 // (half=1, kk=0, p=0)
                }
                // fire-and-forget DMA prefetch of next stage's weight pair
                if (pf) {
                    gload16(&gsrc[nkbase], &Ws[cur ^ 1][t * 8]);
                    gload16(&gsrc[nkbase + 32], &Ws[cur ^ 1][2048 + t * 8]);
                }
#pragma unroll
                for (int b = 0; b < 2; b++) {
                    int cs = 2 * p + b;
                    s8v a[4], bb[4];
#pragma unroll
                    for (int i = 0; i < 4; i++) {
                        int row = i * 16 + rl;
                        int idx = row * 32 + kseg * 8;
                        idx ^= ((idx >> 6) & 3) << 3;
                        a[i] = *(const s8v*)&Ws[cur][b * 2048 + idx];
                    }
                    int u0 = cs * 4 + kseg;
#pragma unroll
                    for (int j = 0; j < 4; j++) {
                        int up = u0 ^ (spix[j] & 7);
                        bb[j] = *(const s8v*)&Ibuf[spix[j] * 128 + up * 8];
                    }
#pragma unroll
                    for (int i = 0; i < 4; i++)
#pragma unroll
                        for (int j = 0; j < 4; j++)
                            acc[i][j] = MFMA16(a[i], bb[j], acc[i][j]);
                }
                __syncthreads();
                cur ^= 1;
            }
        }
    }
    int rq = lane >> 4;
#pragma unroll
    for (int i = 0; i < 4; i++) {
        int m = m0 + i * 16 + rq * 4;
        float b0 = bias[m], b1 = bias[m + 1], b2v = bias[m + 2], b3 = bias[m + 3];
#pragma unroll
        for (int j = 0; j < 4; j++) {
            int col = (j * 4 + wave) * 16 + rl;
            if (col >= 196) continue;
            u64 pack = (u64)f2b(fmaxf(acc[i][j][0] + b0, 0.0f))
                     | ((u64)f2b(fmaxf(acc[i][j][1] + b1, 0.0f)) << 16)
                     | ((u64)f2b(fmaxf(acc[i][j][2] + b2v, 0.0f)) << 32)
                     | ((u64)f2b(fmaxf(acc[i][j][3] + b3, 0.0f)) << 48);
            *(u64*)&Out[(size_t)(roi * 196 + col) * 256 + m] = pack;
        }
    }
}

// ---------------- bf16 MFMA deconv: M=1024 (o*4+d), K=256, out f32 NCHW 28x28 ----------------
__global__ __launch_bounds__(256) void deconv_mfma_k(const ushort_t* __restrict__ Wb,
        const ushort_t* __restrict__ In, const float* __restrict__ bias,
        float* __restrict__ Out, int NC) {
    __shared__ __align__(16) ushort_t As[2048];
    __shared__ __align__(16) ushort_t Bs[2048];
    int t = threadIdx.x;
    int wave = t >> 6, lane = t & 63;
    int wm = wave >> 1, wn = wave & 1;
    int m0 = blockIdx.y * 64, n0 = blockIdx.x * 64;
    f4v acc[2][2] = {};
    int arow = t >> 2, akseg = t & 3;
    int bcol = t & 63, bkseg = t >> 6;
    int colg = n0 + bcol;
    bool colok = colg < NC;
    int rl = lane & 15, kseg = lane >> 4;

    for (int k0 = 0; k0 < 256; k0 += 32) {
        {
            int idx = arow * 32 + akseg * 8;
            int sidx = idx ^ (((idx >> 6) & 3) << 3);
            *(s8v*)&As[sidx] = *(const s8v*)&Wb[(size_t)(m0 + arow) * 256 + k0 + akseg * 8];
        }
        {
            s8v v = {0, 0, 0, 0, 0, 0, 0, 0};
            if (colok)
                v = *(const s8v*)&In[(size_t)colg * 256 + k0 + bkseg * 8];
            int idx = bcol * 32 + bkseg * 8;
            int sidx = idx ^ (((idx >> 6) & 3) << 3);
            *(s8v*)&Bs[sidx] = v;
        }
        __syncthreads();
        s8v a[2], b[2];
#pragma unroll
        for (int i = 0; i < 2; i++) {
            int row = wm * 32 + i * 16 + rl;
            int idx = row * 32 + kseg * 8;
            idx ^= ((idx >> 6) & 3) << 3;
            a[i] = *(const s8v*)&As[idx];
        }
#pragma unroll
        for (int j = 0; j < 2; j++) {
            int col = wn * 32 + j * 16 + rl;
            int idx = col * 32 + kseg * 8;
            idx ^= ((idx >> 6) & 3) << 3;
            b[j] = *(const s8v*)&Bs[idx];
        }
#pragma unroll
        for (int i = 0; i < 2; i++)
#pragma unroll
            for (int j = 0; j < 2; j++)
                acc[i][j] = MFMA16(a[i], b[j], acc[i][j]);
        __syncthreads();
    }
    int rq = lane >> 4;
#pragma unroll
    for (int i = 0; i < 2; i++) {
#pragma unroll
        for (int j = 0; j < 2; j++) {
            int col = n0 + wn * 32 + j * 16 + rl;
            if (col >= NC) continue;
            int n = col / 196;
            int p = col - n * 196;
            int y = p / 14, x = p - y * 14;
            int m = m0 + wm * 32 + i * 16 + rq * 4;
            int o = m >> 2;
            float bv = bias[o];
            float2 lo, hi;
            lo.x = fmaxf(acc[i][j][0] + bv, 0.0f);
            lo.y = fmaxf(acc[i][j][1] + bv, 0.0f);
            hi.x = fmaxf(acc[i][j][2] + bv, 0.0f);
            hi.y = fmaxf(acc[i][j][3] + bv, 0.0f);
            size_t base = ((size_t)n * 256 + o) * 784;
            *(float2*)&Out[base + (size_t)(2 * y) * 28 + 2 * x] = lo;
            *(float2*)&Out[base + (size_t)(2 * y + 1) * 28 + 2 * x] = hi;
        }
    }
}

// ---------------- softmax over 81 + box decode for classes 1..80 ----------------
__global__ __launch_bounds__(128) void softmax_decode_k(const float* __restrict__ logits,
        const float* __restrict__ reg, const float* __restrict__ bbox,
        float* __restrict__ scores_c, float* __restrict__ boxes_c) {
    int n = blockIdx.x, t = threadIdx.x;
    __shared__ float sl[81];
    __shared__ float red[128];
    if (t < 81) sl[t] = logits[n * 81 + t];
    __syncthreads();
    red[t] = (t < 81) ? sl[t] : -3.0e38f;
    __syncthreads();
    for (int s = 64; s > 0; s >>= 1) { if (t < s) red[t] = fmaxf(red[t], red[t + s]); __syncthreads(); }
    float mx = red[0];
    __syncthreads();
    float e = (t < 81) ? expf(sl[t] - mx) : 0.0f;
    red[t] = e;
    __syncthreads();
    for (int s = 64; s > 0; s >>= 1) { if (t < s) red[t] += red[t + s]; __syncthreads(); }
    float sum = red[0];
    if (t >= 1 && t < 81) {
        float score = e / sum;
        float bx1 = bbox[n * 4 + 0], by1 = bbox[n * 4 + 1];
        float bx2 = bbox[n * 4 + 2], by2 = bbox[n * 4 + 3];
        float w = bx2 - bx1 + 1.0f, h = by2 - by1 + 1.0f;
        float cx = bx1 + 0.5f * w, cy = by1 + 0.5f * h;
        const float* dn = reg + (size_t)n * 324 + t * 4;
        float dx = dn[0] / 10.0f;
        float dy = dn[1] / 10.0f;
        float dw = fminf(dn[2] / 5.0f, CLAMPV);
        float dh = fminf(dn[3] / 5.0f, CLAMPV);
        float pcx = dx * w + cx, pcy = dy * h + cy;
        float pw = expf(dw) * w, ph = expf(dh) * h;
        float x1 = fminf(fmaxf(pcx - 0.5f * pw, 0.0f), 799.0f);
        float y1 = fminf(fmaxf(pcy - 0.5f * ph, 0.0f), 799.0f);
        float x2 = fminf(fmaxf(pcx + 0.5f * pw - 1.0f, 0.0f), 799.0f);
        float y2 = fminf(fmaxf(pcy + 0.5f * ph - 1.0f, 0.0f), 799.0f);
        int cc = t - 1;
        scores_c[cc * 512 + n] = score;
        float* bo = boxes_c + ((size_t)cc * 512 + n) * 4;
        bo[0] = x1; bo[1] = y1; bo[2] = x2; bo[3] = y2;
    }
}

// ---------------- per-class NMS, score-filtered; compact candidate append ----------------
__global__ __launch_bounds__(256) void nms_k(const float* __restrict__ scores_c,
        const float* __restrict__ boxes_c, u64* __restrict__ cand, int* __restrict__ cnt) {
    int c = blockIdx.x, t = threadIdx.x;
    int lane = t & 63, wave = t >> 6;
    __shared__ float s[512];
    __shared__ float fs[512];
    __shared__ short fidx[512];
    __shared__ float4 ob[512];
    __shared__ short sidx[512];
    __shared__ u64 mask[512][8];
    __shared__ u64 remw[8];
    __shared__ unsigned char stat[512];
    __shared__ int mcnt;
    if (t == 0) mcnt = 0;
    for (int i = t; i < 512; i += 256) {
        s[i] = scores_c[c * 512 + i];
        stat[i] = 0;
    }
    __syncthreads();
    for (int i = t; i < 512; i += 256) {
        if (s[i] > SCORE_THR) {
            int p = atomicAdd(&mcnt, 1);
            fs[p] = s[i];
            fidx[p] = (short)i;
        }
    }
    __syncthreads();
    int m = mcnt;
    if (m > 0) {
        for (int i = t; i < m; i += 256) {
            float si = fs[i];
            int ii = fidx[i];
            int r = 0;
            for (int j = 0; j < m; j++) {
                float sj = fs[j];
                r += (sj > si) || (sj == si && fidx[j] < ii);
            }
            sidx[r] = (short)ii;
        }
        __syncthreads();
        for (int r = t; r < m; r += 256)
            ob[r] = *(const float4*)(boxes_c + ((size_t)c * 512 + sidx[r]) * 4);
        __syncthreads();
        int W = (m + 63) >> 6;
        for (int i = wave; i < m; i += 4) {
            float4 a = ob[i];
            float aarea = (a.z - a.x + 1.0f) * (a.w - a.y + 1.0f);
            for (int b = 0; b < W; b++) {
                int j = b * 64 + lane;
                float4 bb = ob[j < m ? j : 0];
                float barea = (bb.z - bb.x + 1.0f) * (bb.w - bb.y + 1.0f);
                float lx = fmaxf(a.x, bb.x), lyv = fmaxf(a.y, bb.y);
                float rx = fminf(a.z, bb.z), ry = fminf(a.w, bb.w);
                float iw = fmaxf(rx - lx + 1.0f, 0.0f);
                float ih = fmaxf(ry - lyv + 1.0f, 0.0f);
                float inter = iw * ih;
                float iou = inter / (aarea + barea - inter);
                u64 bal = __ballot((j < m) && (j > i) && (iou > NMS_THR));
                if (lane == 0) mask[i][b] = bal;
            }
        }
        __syncthreads();
        if (wave == 0) {
            u64 rm = 0;
            for (int i = 0; i < m; i++) {
                u64 w = shfl64(rm, i >> 6);
                if (!((w >> (i & 63)) & 1ull) && lane < W) rm |= mask[i][lane];
            }
            if (lane < 8) remw[lane] = rm;
        }
        __syncthreads();
        for (int r = t; r < m; r += 256) {
            bool kept = !((remw[r >> 6] >> (r & 63)) & 1ull);
            if (kept) stat[sidx[r]] = 1;
        }
        __syncthreads();
    }
    // append: all positives, plus class-0 flats 0..199 as the -1.0 pad pool.
    for (int i = t; i < 512; i += 256) {
        float val = stat[i] ? s[i] : -1.0f;
        if ((c == 0 && i < 200) || val != -1.0f) {
            int flat = c * 512 + i;
            u32 u = __float_as_uint(val);
            u = (u & 0x80000000u) ? ~u : (u | 0x80000000u);
            u64 key = ((u64)u << 32) | (u64)(0xFFFFFFFFu - (u32)flat);
            int pos = atomicAdd(cnt, 1);
            cand[pos] = key;
        }
    }
}

// ---------------- top-100 via parallel rank selection (keys strictly unique) ----------------
#define TCAP 8192
#define TCHUNK (TCAP - 128)
__global__ __launch_bounds__(512) void topk3_k(const u64* __restrict__ cand,
        const int* __restrict__ cnt, const float* __restrict__ boxes_c,
        float* __restrict__ out) {
    __shared__ u64 ck[TCAP];
    __shared__ u64 wk[100];
    int t = threadIdx.x;
    int n = *cnt;
    for (int i = t; i < 100; i += 512) wk[i] = 0;
    __syncthreads();
    for (int base = 0; base < n; base += TCHUNK) {
        int sz = min(n - base, TCHUNK);
        for (int i = t; i < 100; i += 512) ck[i] = wk[i];
        for (int i = t; i < sz; i += 512) ck[100 + i] = cand[base + i];
        int tot = 100 + sz;
        __syncthreads();
        for (int i = t; i < tot; i += 512) {
            u64 ki = ck[i];
            int r = 0;
            for (int j = 0; j < tot; j++) {
                u64 kj = ck[j];
                r += (kj > ki) || (kj == ki && j < i);
                if (r >= 100) break;
            }
            if (r < 100) wk[r] = ki;
        }
        __syncthreads();
    }
    if (t < 100) {
        u64 bk = wk[t];
        u32 flat = 0xFFFFFFFFu - (u32)(bk & 0xFFFFFFFFull);
        u32 u = (u32)(bk >> 32);
        float val = (u & 0x80000000u) ? __uint_as_float(u & 0x7FFFFFFFu)
                                      : __uint_as_float(~u);
        int cls = (int)(flat >> 9);
        out[t * 4 + 0] = boxes_c[(size_t)flat * 4 + 0];
        out[t * 4 + 1] = boxes_c[(size_t)flat * 4 + 1];
        out[t * 4 + 2] = boxes_c[(size_t)flat * 4 + 2];
        out[t * 4 + 3] = boxes_c[(size_t)flat * 4 + 3];
        out[400 + t] = (float)(cls + 1);
        out[78900 + t] = fmaxf(val, 0.0f);
    }
}

// ---------------- mask head stage 1: partial dot over 32 channels ----------------
__global__ __launch_bounds__(256) void mask_part_k(const float* __restrict__ D,
        const float* __restrict__ w2, const float* __restrict__ out,
        float* __restrict__ MP) {
    int n = blockIdx.x, q = blockIdx.y, t = threadIdx.x;
    int lab = (int)(out[400 + n] + 0.5f);
    __shared__ float wsh[32];
    if (t < 32) wsh[t] = w2[lab * 256 + q * 32 + t];
    __syncthreads();
    const float* Dn = D + (size_t)n * 256 * 784 + (size_t)q * 32 * 784;
    float a0 = 0.0f, a1 = 0.0f, a2 = 0.0f, a3 = 0.0f;
    for (int o = 0; o < 32; o++) {
        float wv = wsh[o];
        const float* Dp = Dn + o * 784;
        a0 += Dp[t] * wv;
        a1 += Dp[t + 256] * wv;
        a2 += Dp[t + 512] * wv;
        if (t < 16) a3 += Dp[t + 768] * wv;
    }
    float* mp = MP + ((size_t)n * 8 + q) * 784;
    mp[t] = a0;
    mp[t + 256] = a1;
    mp[t + 512] = a2;
    if (t < 16) mp[t + 768] = a3;
}

// ---------------- mask head stage 2: sum 8 partials + bias + sigmoid ----------------
__global__ __launch_bounds__(256) void mask_fin_k(const float* __restrict__ MP,
        const float* __restrict__ b2, float* __restrict__ out) {
    int n = blockIdx.x, t = threadIdx.x;
    int lab = (int)(out[400 + n] + 0.5f);
    float bb = b2[lab];
    const float* mp = MP + (size_t)n * 8 * 784;
    for (int p = t; p < 784; p += 256) {
        float s = 0.0f;
#pragma unroll
        for (int q = 0; q < 8; q++) s += mp[q * 784 + p];
        s += bb;
        out[500 + n * 784 + p] = 1.0f / (1.0f + expf(-s));
    }
}

extern "C" void kernel_launch(void* const* d_in, const int* in_sizes, int n_in,
                              void* d_out, int out_size, void* d_ws, size_t ws_size,
                              hipStream_t stream) {
    const float* features = (const float*)d_in[0];
    const float* bbox = (const float*)d_in[1];
    const float* fc1_w = (const float*)d_in[3];
    const float* fc1_b = (const float*)d_in[4];
    const float* fc2_w = (const float*)d_in[5];
    const float* fc2_b = (const float*)d_in[6];
    const float* cls_w = (const float*)d_in[7];
    const float* cls_b = (const float*)d_in[8];
    const float* reg_w = (const float*)d_in[9];
    const float* reg_b = (const float*)d_in[10];
    const float* mc1w = (const float*)d_in[11];
    const float* mc1b = (const float*)d_in[12];
    const float* mc2w = (const float*)d_in[13];
    const float* mc2b = (const float*)d_in[14];
    const float* mc3w = (const float*)d_in[15];
    const float* mc3b = (const float*)d_in[16];
    const float* mc4w = (const float*)d_in[17];
    const float* mc4b = (const float*)d_in[18];
    const float* dcw = (const float*)d_in[19];
    const float* dcb = (const float*)d_in[20];
    const float* mpw = (const float*)d_in[21];
    const float* mpb = (const float*)d_in[22];
    float* out = (float*)d_out;
    float* ws = (float*)d_ws;

    // ---- workspace layout (float offsets), time-multiplexed ----
    float* FEAT = ws + 0;
    float* D    = ws + 0;                         // mask phase (deconv out)
    ushort_t* XFh = (ushort_t*)(ws + 10240000);
    ushort_t* XFl = (ushort_t*)(ws + 13451264);
    ushort_t* W1h = (ushort_t*)(ws + 16662528);
    ushort_t* W1l = (ushort_t*)(ws + 23085056);   // [.. 29,507,584)
    ushort_t* H1h = (ushort_t*)(ws + 16662528);
    ushort_t* H1l = (ushort_t*)(ws + 16924672);
    ushort_t* H2h = (ushort_t*)(ws + 17186816);
    ushort_t* H2l = (ushort_t*)(ws + 17448960);
    ushort_t* W2h = (ushort_t*)(ws + 17711104);
    ushort_t* W2l = (ushort_t*)(ws + 18235392);
    ushort_t* Wcrh = (ushort_t*)(ws + 18759680);
    ushort_t* Wcrl = (ushort_t*)(ws + 18967040);
    float* LOGI = ws + 19174400;
    float* REG  = ws + 19215872;
    float* BXC  = ws + 19381760;
    float* SCC  = ws + 19545600;
    u64*  CAND  = (u64*)(ws + 19586560);
    int*  CNT   = (int*)(ws + 19670000);
    ushort_t* Abf = (ushort_t*)(ws + 20070400);   // mask phase
    ushort_t* Bbf = (ushort_t*)(ws + 22579200);
    ushort_t* W1b = (ushort_t*)(ws + 25088000);
    ushort_t* W2b = (ushort_t*)(ws + 25382912);
    ushort_t* W3b = (ushort_t*)(ws + 25677824);
    ushort_t* W4b = (ushort_t*)(ws + 25972736);
    ushort_t* WDb = (ushort_t*)(ws + 26267648);   // ends 26,398,720
    float* MP   = ws + 26398720;

    // if the workspace is large enough, put GEMM partials ABOVE the peak
    // region [29,507,584 .. 33,701,888) so FEAT at ws+0 survives the whole
    // detect phase -> second transpose deleted. Fallback = old layout.
    bool bigws = ws_size >= (size_t)33701888 * sizeof(float);
    float* PARTg = bigws ? (ws + 29507584) : (ws + 0);

    transpose_k<<<dim3(1250, 8), dim3(32, 8), 0, stream>>>(features, FEAT, 256, 40000);
    cvt_w1_k<<<1024, 256, 0, stream>>>(fc1_w, W1h, W1l);
    roi_align_hilo_k<<<dim3(49, 512), 256, 0, stream>>>(FEAT, bbox, XFh, XFl);
    // (non-bigws: FEAT dead from here; PARTg overlays it.)

    // fc1: 128x128-tile K-blocked 3-buffer counted-vmcnt kernel, XCD-aware grid:
    // launched (z, x, y) so the K-chunk is the fastest dim -> one XCD per chunk.
    gemm128_k<<<dim3(8, 8, 4), 512, 0, stream>>>(XFh, XFl, W1h, W1l, PARTg, 512, 1024, 392, 49);
    reduce2_k<<<2048, 256, 0, stream>>>(PARTg, fc1_b, (float*)nullptr, H1h, H1l, 512, 1024, 8, 1);

    cvt_hilo3_k<<<5716, 256, 0, stream>>>(fc2_w, cls_w, reg_w, W2h, W2l,
            Wcrh, Wcrl, Wcrh + 81 * 1024, Wcrl + 81 * 1024);
    cvt_allw_k<<<10240, 256, 0, stream>>>(mc1w, mc2w, mc3w, mc4w, dcw, W1b, W2b, W3b, W4b, WDb, CNT);

    gemm3_mfma_k<<<dim3(16, 8, 8), 256, 0, stream>>>(H1h, H1l, W2h, W2l, PARTg, 512, 1024, 1024, 128);
    reduce2_k<<<2048, 256, 0, stream>>>(PARTg, fc2_b, (float*)nullptr, H2h, H2l, 512, 1024, 8, 1);
    gemm3_mfma_k<<<dim3(7, 8, 8), 256, 0, stream>>>(H2h, H2l, Wcrh, Wcrl, PARTg, 512, 405, 1024, 128);
    reduce_cr_k<<<810, 256, 0, stream>>>(PARTg, cls_b, reg_b, LOGI, REG);
    // PARTg dead from here.

    softmax_decode_k<<<512, 128, 0, stream>>>(LOGI, REG, bbox, SCC, BXC);
    nms_k<<<80, 256, 0, stream>>>(SCC, BXC, CAND, CNT);
    topk3_k<<<1, 512, 0, stream>>>(CAND, CNT, BXC, out);

    // mask branch
    if (!bigws) {  // FEAT was overwritten by partials: re-transpose
        transpose_k<<<dim3(1250, 8), dim3(32, 8), 0, stream>>>(features, FEAT, 256, 40000);
    }
    roi_align_mask_k<<<dim3(196, 100), 256, 0, stream>>>(FEAT, out, Abf);
    conv3_roi_k<<<416, 256, 0, stream>>>(W1b, Abf, mc1b, Bbf);
    conv3_roi_k<<<416, 256, 0, stream>>>(W2b, Bbf, mc2b, Abf);
    conv3_roi_k<<<416, 256, 0, stream>>>(W3b, Abf, mc3b, Bbf);
    conv3_roi_k<<<416, 256, 0, stream>>>(W4b, Bbf, mc4b, Abf);
    deconv_mfma_k<<<dim3(307, 16), 256, 0, stream>>>(WDb, Abf, dcb, D, 19600);
    mask_part_k<<<dim3(100, 8), 256, 0, stream>>>(D, mpw, out, MP);
    mask_fin_k<<<100, 256, 0, stream>>>(MP, mpb, out);
}

// Round 14
// 459.913 us; speedup vs baseline: 1.0162x; 1.0162x over previous
//
#include <hip/hip_runtime.h>
#include <cstdint>
#include <cstddef>

typedef unsigned long long u64;
typedef unsigned int u32;
typedef unsigned short ushort_t;
typedef __attribute__((ext_vector_type(8))) short s8v;
typedef __attribute__((ext_vector_type(4))) float f4v;

#define NMS_THR 0.5f
#define SCORE_THR 0.05f
#define CLAMPV 4.135166556742356f
#define MFMA16(a,b,c) __builtin_amdgcn_mfma_f32_16x16x32_bf16(a,b,c,0,0,0)

static __device__ inline ushort_t f2b(float f) {
    u32 u = __float_as_uint(f);
    return (ushort_t)((u + 0x7FFFu + ((u >> 16) & 1u)) >> 16);
}
static __device__ inline float b2f(ushort_t h) {
    return __uint_as_float((u32)h << 16);
}
static __device__ inline u64 shfl64(u64 v, int src) {
    int lo = __shfl((int)(u32)v, src, 64);
    int hi = __shfl((int)(u32)(v >> 32), src, 64);
    return ((u64)(u32)hi << 32) | (u64)(u32)lo;
}
// direct global->LDS DMA, 16B per lane. LDS dest is wave-uniform base + lane*16.
static __device__ __forceinline__ void gload16(const void* g, void* l) {
    __builtin_amdgcn_global_load_lds(
        (const __attribute__((address_space(1))) void*)g,
        (__attribute__((address_space(3))) void*)l, 16, 0, 0);
}

// ---------------- transpose (rows, cols) -> (cols, rows) ----------------
__global__ __launch_bounds__(256) void transpose_k(const float* __restrict__ in,
        float* __restrict__ out, int rows, int cols) {
    __shared__ float tile[32][33];
    int c0 = blockIdx.x * 32, r0 = blockIdx.y * 32;
    int tx = threadIdx.x, ty = threadIdx.y;
#pragma unroll
    for (int i = 0; i < 32; i += 8) {
        int r = r0 + ty + i, c = c0 + tx;
        if (r < rows && c < cols) tile[ty + i][tx] = in[(size_t)r * cols + c];
    }
    __syncthreads();
#pragma unroll
    for (int i = 0; i < 32; i += 8) {
        int r = c0 + ty + i, c = r0 + tx;
        if (r < cols && c < rows) out[(size_t)r * rows + c] = tile[tx][ty + i];
    }
}

// ---------------- weight converts ----------------
// fc1 weight in K-BLOCKED layout: [panel p=o>>7][kstep=k'>>5][row=o&127][32].
__global__ __launch_bounds__(256) void cvt_w1_k(const float* __restrict__ w,
        ushort_t* __restrict__ Wh, ushort_t* __restrict__ Wl) {
    __shared__ float row[12544];
    int o = blockIdx.x;
    const float* src = w + (size_t)o * 12544;
    for (int i = threadIdx.x; i < 12544; i += 256) row[i] = src[i];
    __syncthreads();
    int p = o >> 7, r = o & 127;
    for (int i = threadIdx.x; i < 12544; i += 256) {
        int s = i >> 8, c = i & 255;
        float v = row[c * 49 + s];
        ushort_t h = f2b(v);
        ushort_t l = f2b(v - b2f(h));
        size_t idx = ((size_t)(p * 392 + (i >> 5)) << 12) + (r << 5) + (i & 31);
        Wh[idx] = h;
        Wl[idx] = l;
    }
}

// fused hi/lo split for fc2 (1048576) + cls (82944) + reg (331776)
__global__ __launch_bounds__(256) void cvt_hilo3_k(const float* __restrict__ w2,
        const float* __restrict__ wc, const float* __restrict__ wr,
        ushort_t* __restrict__ h2, ushort_t* __restrict__ l2,
        ushort_t* __restrict__ hc, ushort_t* __restrict__ lc,
        ushort_t* __restrict__ hr, ushort_t* __restrict__ lr) {
    int i = blockIdx.x * 256 + threadIdx.x;
    const float* w; ushort_t* h; ushort_t* l; int r;
    if (i < 1048576) { w = w2; h = h2; l = l2; r = i; }
    else if (i < 1131520) { w = wc; h = hc; l = lc; r = i - 1048576; }
    else if (i < 1463296) { w = wr; h = hr; l = lr; r = i - 1131520; }
    else return;
    float v = w[r];
    ushort_t hh = f2b(v);
    h[r] = hh;
    l[r] = f2b(v - b2f(hh));
}

// fused conv weights (4 x 589824) + deconv (262144) convert; also zeroes CNT
__global__ __launch_bounds__(256) void cvt_allw_k(const float* __restrict__ w1,
        const float* __restrict__ w2, const float* __restrict__ w3,
        const float* __restrict__ w4, const float* __restrict__ wd,
        ushort_t* __restrict__ o1, ushort_t* __restrict__ o2,
        ushort_t* __restrict__ o3, ushort_t* __restrict__ o4,
        ushort_t* __restrict__ od, int* __restrict__ cnt) {
    int t = blockIdx.x * 256 + threadIdx.x;
    if (t == 0) *cnt = 0;
    if (t < 2359296) {
        int which = t / 589824;
        int r = t - which * 589824;
        const float* w = (which == 0) ? w1 : (which == 1) ? w2 : (which == 2) ? w3 : w4;
        ushort_t* o = (which == 0) ? o1 : (which == 1) ? o2 : (which == 2) ? o3 : o4;
        int oc = r / 2304;
        int rem = r - oc * 2304;
        int kk = rem >> 8;
        int ci = rem & 255;
        o[r] = f2b(w[oc * 2304 + ci * 9 + kk]);
    } else {
        int r = t - 2359296;
        if (r < 262144) {
            int m = r >> 8;
            int ci = r & 255;
            od[r] = f2b(wd[ci * 1024 + m]);
        }
    }
}

// ---------------- roi align (FC path): hi/lo bf16 out, K-blocked layout ----------------
__global__ __launch_bounds__(256) void roi_align_hilo_k(const float* __restrict__ feat,
        const float* __restrict__ rois, ushort_t* __restrict__ outh,
        ushort_t* __restrict__ outl) {
    int c = threadIdx.x;
    int s = blockIdx.x;
    int n = blockIdx.y;
    const int P = 7;
    int py = s / P, px = s - py * P;
    float rx1 = rois[n * 4 + 0] * 0.25f;
    float ry1 = rois[n * 4 + 1] * 0.25f;
    float rx2 = rois[n * 4 + 2] * 0.25f;
    float ry2 = rois[n * 4 + 3] * 0.25f;
    float bw = fmaxf(rx2 - rx1, 1.0f) / (float)P;
    float bh = fmaxf(ry2 - ry1, 1.0f) / (float)P;
    float acc = 0.0f;
#pragma unroll
    for (int sy = 0; sy < 2; sy++)
#pragma unroll
        for (int sx = 0; sx < 2; sx++) {
            float y = ry1 + ((float)py + ((float)sy + 0.5f) * 0.5f) * bh;
            float x = rx1 + ((float)px + ((float)sx + 0.5f) * 0.5f) * bw;
            y = fminf(fmaxf(y, 0.0f), 199.0f);
            x = fminf(fmaxf(x, 0.0f), 199.0f);
            float y0f = floorf(y), x0f = floorf(x);
            float ly = y - y0f, lx = x - x0f;
            int y0 = (int)y0f, x0 = (int)x0f;
            int y1 = min(y0 + 1, 199), x1 = min(x0 + 1, 199);
            float v00 = feat[((size_t)(y0 * 200 + x0)) * 256 + c];
            float v01 = feat[((size_t)(y0 * 200 + x1)) * 256 + c];
            float v10 = feat[((size_t)(y1 * 200 + x0)) * 256 + c];
            float v11 = feat[((size_t)(y1 * 200 + x1)) * 256 + c];
            acc += v00 * (1.0f - ly) * (1.0f - lx) + v01 * (1.0f - ly) * lx
                 + v10 * ly * (1.0f - lx) + v11 * ly * lx;
        }
    float v = acc * 0.25f;
    ushort_t h = f2b(v);
    int kp = s * 256 + c;                       // k' index
    size_t idx = ((size_t)((n >> 7) * 392 + (kp >> 5)) << 12)
               + ((n & 127) << 5) + (kp & 31);
    outh[idx] = h;
    outl[idx] = f2b(v - b2f(h));
}

// ---------------- roi align (mask path), bf16 channels-last out ----------------
__global__ __launch_bounds__(256) void roi_align_mask_k(const float* __restrict__ feat,
        const float* __restrict__ dets, ushort_t* __restrict__ out) {
    int c = threadIdx.x;
    int s = blockIdx.x;
    int n = blockIdx.y;
    const int P = 14;
    int py = s / P, px = s - py * P;
    float rx1 = dets[n * 4 + 0] * 0.25f;
    float ry1 = dets[n * 4 + 1] * 0.25f;
    float rx2 = dets[n * 4 + 2] * 0.25f;
    float ry2 = dets[n * 4 + 3] * 0.25f;
    float bw = fmaxf(rx2 - rx1, 1.0f) / (float)P;
    float bh = fmaxf(ry2 - ry1, 1.0f) / (float)P;
    float acc = 0.0f;
#pragma unroll
    for (int sy = 0; sy < 2; sy++)
#pragma unroll
        for (int sx = 0; sx < 2; sx++) {
            float y = ry1 + ((float)py + ((float)sy + 0.5f) * 0.5f) * bh;
            float x = rx1 + ((float)px + ((float)sx + 0.5f) * 0.5f) * bw;
            y = fminf(fmaxf(y, 0.0f), 199.0f);
            x = fminf(fmaxf(x, 0.0f), 199.0f);
            float y0f = floorf(y), x0f = floorf(x);
            float ly = y - y0f, lx = x - x0f;
            int y0 = (int)y0f, x0 = (int)x0f;
            int y1 = min(y0 + 1, 199), x1 = min(x0 + 1, 199);
            float v00 = feat[((size_t)(y0 * 200 + x0)) * 256 + c];
            float v01 = feat[((size_t)(y0 * 200 + x1)) * 256 + c];
            float v10 = feat[((size_t)(y1 * 200 + x0)) * 256 + c];
            float v11 = feat[((size_t)(y1 * 200 + x1)) * 256 + c];
            acc += v00 * (1.0f - ly) * (1.0f - lx) + v01 * (1.0f - ly) * lx
                 + v10 * ly * (1.0f - lx) + v11 * ly * lx;
        }
    out[((size_t)n * 196 + s) * 256 + c] = f2b(acc * 0.25f);
}

// ---------------- error-compensated bf16 MFMA split-K GEMM (64-tile) ----------------
// (kept for fc2 / cls+reg; fc1 uses gemm128_k below)
__global__ __launch_bounds__(256) void gemm3_mfma_k(const ushort_t* __restrict__ Ah,
        const ushort_t* __restrict__ Al, const ushort_t* __restrict__ Bh,
        const ushort_t* __restrict__ Bl, float* __restrict__ P,
        int M, int N, int K, int kchunk) {
    __shared__ __align__(16) ushort_t AsH[2048], AsL[2048], BsH[2048], BsL[2048];
    int t = threadIdx.x;
    int wave = t >> 6, lane = t & 63;
    int wm = wave >> 1, wn = wave & 1;
    int m0 = blockIdx.y * 64, n0 = blockIdx.x * 64;
    int z = blockIdx.z;
    int kb = z * kchunk, ke = min(K, kb + kchunk);
    f4v acc[2][2] = {};
    int rl = lane & 15, kseg = lane >> 4;
    // source pre-swizzle: LDS granule t holds global granule t^((t>>3)&3)
    int gsw = t ^ ((t >> 3) & 3);
    int grow = gsw >> 2, gseg = gsw & 3;
    size_t aoff = (size_t)(m0 + grow) * K + gseg * 8;
    size_t boff = (size_t)(n0 + grow) * K + gseg * 8;
    for (int k0 = kb; k0 < ke; k0 += 32) {
        gload16(&Ah[aoff + k0], &AsH[t * 8]);
        gload16(&Al[aoff + k0], &AsL[t * 8]);
        gload16(&Bh[boff + k0], &BsH[t * 8]);
        gload16(&Bl[boff + k0], &BsL[t * 8]);
        __syncthreads();
        s8v ah[2], al[2], bh[2], bl[2];
#pragma unroll
        for (int i = 0; i < 2; i++) {
            int row = wm * 32 + i * 16 + rl;
            int idx = row * 32 + kseg * 8;
            idx ^= ((idx >> 6) & 3) << 3;
            ah[i] = *(const s8v*)&AsH[idx];
            al[i] = *(const s8v*)&AsL[idx];
        }
#pragma unroll
        for (int j = 0; j < 2; j++) {
            int col = wn * 32 + j * 16 + rl;
            int idx = col * 32 + kseg * 8;
            idx ^= ((idx >> 6) & 3) << 3;
            bh[j] = *(const s8v*)&BsH[idx];
            bl[j] = *(const s8v*)&BsL[idx];
        }
#pragma unroll
        for (int i = 0; i < 2; i++)
#pragma unroll
            for (int j = 0; j < 2; j++) {
                acc[i][j] = MFMA16(al[i], bh[j], acc[i][j]);
                acc[i][j] = MFMA16(ah[i], bl[j], acc[i][j]);
                acc[i][j] = MFMA16(ah[i], bh[j], acc[i][j]);
            }
        __syncthreads();
    }
    float* Pz = P + (size_t)z * M * N;
    int rq = lane >> 4;
#pragma unroll
    for (int i = 0; i < 2; i++) {
#pragma unroll
        for (int j = 0; j < 2; j++) {
            int col = n0 + wn * 32 + j * 16 + rl;
            if (col >= N) continue;
            int m = m0 + wm * 32 + i * 16 + rq * 4;
#pragma unroll
            for (int r = 0; r < 4; r++)
                Pz[(size_t)(m + r) * N + col] = acc[i][j][r];
        }
    }
}

// ---------------- 128x128-tile hi/lo GEMM for fc1, K-blocked operands ----------------
// R14: reverted to the proven R12 2-buffer pipeline (R13's 3-buffer counted
// vmcnt REGRESSED 57.2->60.4: fc1 is LDS-throughput/lockstep-bound, not
// barrier-drain-bound; extra LDS+VGPR pressure hurt). XCD-aware grid
// (z fastest). K-blocked operands (8KB contiguous tiles).
__global__ __launch_bounds__(512) void gemm128_k(const ushort_t* __restrict__ Ah,
        const ushort_t* __restrict__ Al, const ushort_t* __restrict__ Bh,
        const ushort_t* __restrict__ Bl, float* __restrict__ P,
        int M, int N, int nsteps_total, int chunk_steps) {
    __shared__ __align__(16) ushort_t AsH[2][4096], AsL[2][4096], BsH[2][4096], BsL[2][4096];
    int t = threadIdx.x;
    int wave = t >> 6, lane = t & 63;
    int wm = wave >> 2, wn = wave & 3;          // 2 x 4 wave grid, wave = 64x32
    // grid remap: launched as (z, x, y) so z is fastest -> z maps to XCD
    int z  = blockIdx.x;
    int xb = blockIdx.y;                        // N-block
    int yb = blockIdx.z;                        // M-block
    int sb = z * chunk_steps, se = min(nsteps_total, sb + chunk_steps);
    f4v acc[4][2] = {};
    int rl = lane & 15, kseg = lane >> 4;
    // source pre-swizzle: LDS granule t holds global granule t^((t>>3)&3)
    int gsw = t ^ ((t >> 3) & 3);
    size_t abase = ((size_t)yb * nsteps_total) << 12;
    size_t bbase = ((size_t)xb * nsteps_total) << 12;
    int goff = gsw * 8;
    // prologue: stage step sb into buf 0
    gload16(&Ah[abase + ((size_t)sb << 12) + goff], &AsH[0][t * 8]);
    gload16(&Al[abase + ((size_t)sb << 12) + goff], &AsL[0][t * 8]);
    gload16(&Bh[bbase + ((size_t)sb << 12) + goff], &BsH[0][t * 8]);
    gload16(&Bl[bbase + ((size_t)sb << 12) + goff], &BsL[0][t * 8]);
    __syncthreads();
    int cur = 0;
    for (int ks = sb; ks < se; ks++) {
        if (ks + 1 < se) {
            size_t o = ((size_t)(ks + 1) << 12) + goff;
            gload16(&Ah[abase + o], &AsH[cur ^ 1][t * 8]);
            gload16(&Al[abase + o], &AsL[cur ^ 1][t * 8]);
            gload16(&Bh[bbase + o], &BsH[cur ^ 1][t * 8]);
            gload16(&Bl[bbase + o], &BsL[cur ^ 1][t * 8]);
        }
        s8v ah[4], al[4], bh[2], bl[2];
#pragma unroll
        for (int i = 0; i < 4; i++) {
            int row = wm * 64 + i * 16 + rl;
            int idx = row * 32 + kseg * 8;
            idx ^= ((idx >> 6) & 3) << 3;
            ah[i] = *(const s8v*)&AsH[cur][idx];
            al[i] = *(const s8v*)&AsL[cur][idx];
        }
#pragma unroll
        for (int j = 0; j < 2; j++) {
            int col = wn * 32 + j * 16 + rl;
            int idx = col * 32 + kseg * 8;
            idx ^= ((idx >> 6) & 3) << 3;
            bh[j] = *(const s8v*)&BsH[cur][idx];
            bl[j] = *(const s8v*)&BsL[cur][idx];
        }
#pragma unroll
        for (int i = 0; i < 4; i++)
#pragma unroll
            for (int j = 0; j < 2; j++) {
                acc[i][j] = MFMA16(al[i], bh[j], acc[i][j]);
                acc[i][j] = MFMA16(ah[i], bl[j], acc[i][j]);
                acc[i][j] = MFMA16(ah[i], bh[j], acc[i][j]);
            }
        __syncthreads();
        cur ^= 1;
    }
    float* Pz = P + (size_t)z * M * N;
    int rq = lane >> 4;
    int m0 = yb * 128, n0 = xb * 128;
#pragma unroll
    for (int i = 0; i < 4; i++) {
#pragma unroll
        for (int j = 0; j < 2; j++) {
            int col = n0 + wn * 32 + j * 16 + rl;
            if (col >= N) continue;
            int m = m0 + wm * 64 + i * 16 + rq * 4;
#pragma unroll
            for (int r = 0; r < 4; r++)
                Pz[(size_t)(m + r) * N + col] = acc[i][j][r];
        }
    }
}

// reduce split-K partials + bias (+relu); write f32 and/or hi+lo bf16
__global__ __launch_bounds__(256) void reduce2_k(const float* __restrict__ P,
        const float* __restrict__ bias, float* __restrict__ Cf,
        ushort_t* __restrict__ Ch, ushort_t* __restrict__ Cl,
        int M, int N, int nsplit, int relu) {
    int idx = blockIdx.x * 256 + threadIdx.x;
    if (idx >= M * N) return;
    int n = idx % N;
    float s = 0.0f;
    for (int z = 0; z < nsplit; z++) s += P[(size_t)z * M * N + idx];
    s += bias[n];
    if (relu) s = fmaxf(s, 0.0f);
    if (Cf) Cf[idx] = s;
    if (Ch) {
        ushort_t h = f2b(s);
        Ch[idx] = h;
        Cl[idx] = f2b(s - b2f(h));
    }
}

// reduce for merged cls+reg GEMM (M=512, N=405)
__global__ __launch_bounds__(256) void reduce_cr_k(const float* __restrict__ P,
        const float* __restrict__ cls_b, const float* __restrict__ reg_b,
        float* __restrict__ LOGI, float* __restrict__ REG) {
    int idx = blockIdx.x * 256 + threadIdx.x;
    if (idx >= 512 * 405) return;
    int n = idx / 405, col = idx - n * 405;
    float s = 0.0f;
    for (int z = 0; z < 8; z++) s += P[(size_t)z * 512 * 405 + idx];
    if (col < 81) LOGI[n * 81 + col] = s + cls_b[col];
    else REG[n * 324 + (col - 81)] = s + reg_b[col - 81];
}

// ---------------- roi-resident bf16 MFMA 3x3 conv, LDS weights + global_load_lds ----------------
// R12 structure: zero-pixel sentinel (halo cndmask deleted); R8 paired
// cs-stages (K=64/stage, 36 barriers).
__global__ __launch_bounds__(256) void conv3_roi_k(const ushort_t* __restrict__ Wb,
        const ushort_t* __restrict__ In, const float* __restrict__ bias,
        ushort_t* __restrict__ Out) {
    __shared__ __align__(16) ushort_t Ibuf[200 * 128];
    __shared__ __align__(16) ushort_t Ws[2][4096];   // [buf][cs-parity*2048 + idx]
    int bid = blockIdx.x;
    int roiLow = bid & 7;
    int q = bid >> 3;
    int slice = q & 3;
    int roi = (q >> 2) * 8 + roiLow;
    if (roi >= 100) return;
    int t = threadIdx.x;
    int wave = t >> 6, lane = t & 63;
    int rl = lane & 15, kseg = lane >> 4;
    int m0 = slice * 64;
    f4v acc[4][4] = {};
    int yb[4], xb[4];
    bool cok[4];
#pragma unroll
    for (int j = 0; j < 4; j++) {
        int col = (j * 4 + wave) * 16 + rl;
        cok[j] = col < 196;
        int cc = cok[j] ? col : 0;
        yb[j] = cc / 14;
        xb[j] = cc - yb[j] * 14;
    }
    // zero sentinel pixel row 196 (persists across halves; staging only
    // writes pixels 0..195). 16 threads x 8 ushorts = 128.
    if (t < 16) {
        s8v zz = {0, 0, 0, 0, 0, 0, 0, 0};
        *(s8v*)&Ibuf[196 * 128 + t * 8] = zz;
    }
    // weight staging: LDS granule t holds global granule t^((t>>3)&3)
    int gsw = t ^ ((t >> 3) & 3);
    const ushort_t* gsrc = Wb + (size_t)(m0 + (gsw >> 2)) * 2304 + (gsw & 3) * 8;
    int cur = 0;
    for (int half = 0; half < 2; half++) {
        // Ibuf staging: granule (pix,u) sources (pix, u^(pix&7)) — linear dest
        for (int uidx = t; uidx < 3136; uidx += 256) {
            int pix = uidx >> 4, u = uidx & 15;
            int usw = u ^ (pix & 7);
            gload16(&In[(size_t)(roi * 196 + pix) * 256 + half * 128 + usw * 8],
                    &Ibuf[uidx * 8]);
        }
        if (half == 0) {  // prologue: stage (kk=0, p=0) pair into Ws[0]
            gload16(&gsrc[0], &Ws[0][t * 8]);
            gload16(&gsrc[32], &Ws[0][2048 + t * 8]);
        }
        __syncthreads();
        for (int kk = 0; kk < 9; kk++) {
            int ky = kk / 3, kx = kk - ky * 3;
            int spix[4];
#pragma unroll
            for (int j = 0; j < 4; j++) {
                int iy = yb[j] + ky - 1, ix = xb[j] + kx - 1;
                bool sval = cok[j] && iy >= 0 && iy < 14 && ix >= 0 && ix < 14;
                spix[j] = sval ? (iy * 14 + ix) : 196;   // 196 = zero sentinel
            }
#pragma unroll
            for (int p = 0; p < 2; p++) {
                int s = kk * 2 + p;               // stage index in [0,17]
                bool pf = (s < 17) || (half == 0);
                int nkbase;
                if (s < 17) {
                    int ns = s + 1;
                    nkbase = (ns >> 1) * 256 + half * 128 + (ns & 1) * 64;
                } else {
                    nkbase = 128;                 // (half=1, kk=0, p=0)
                }
                // fire-and-forget DMA prefetch of next stage's weight pair
                if (pf) {
                    gload16(&gsrc[nkbase], &Ws[cur ^ 1][t * 8]);
                    gload16(&gsrc[nkbase + 32], &Ws[cur ^ 1][2048 + t * 8]);
                }
#pragma unroll
                for (int b = 0; b < 2; b++) {
                    int cs = 2 * p + b;
                    s8v a[4], bb[4];
#pragma unroll
                    for (int i = 0; i < 4; i++) {
                        int row = i * 16 + rl;
                        int idx = row * 32 + kseg * 8;
                        idx ^= ((idx >> 6) & 3) << 3;
                        a[i] = *(const s8v*)&Ws[cur][b * 2048 + idx];
                    }
                    int u0 = cs * 4 + kseg;
#pragma unroll
                    for (int j = 0; j < 4; j++) {
                        int up = u0 ^ (spix[j] & 7);
                        bb[j] = *(const s8v*)&Ibuf[spix[j] * 128 + up * 8];
                    }
#pragma unroll
                    for (int i = 0; i < 4; i++)
#pragma unroll
                        for (int j = 0; j < 4; j++)
                            acc[i][j] = MFMA16(a[i], bb[j], acc[i][j]);
                }
                __syncthreads();
                cur ^= 1;
            }
        }
    }
    int rq = lane >> 4;
#pragma unroll
    for (int i = 0; i < 4; i++) {
        int m = m0 + i * 16 + rq * 4;
        float b0 = bias[m], b1 = bias[m + 1], b2v = bias[m + 2], b3 = bias[m + 3];
#pragma unroll
        for (int j = 0; j < 4; j++) {
            int col = (j * 4 + wave) * 16 + rl;
            if (col >= 196) continue;
            u64 pack = (u64)f2b(fmaxf(acc[i][j][0] + b0, 0.0f))
                     | ((u64)f2b(fmaxf(acc[i][j][1] + b1, 0.0f)) << 16)
                     | ((u64)f2b(fmaxf(acc[i][j][2] + b2v, 0.0f)) << 32)
                     | ((u64)f2b(fmaxf(acc[i][j][3] + b3, 0.0f)) << 48);
            *(u64*)&Out[(size_t)(roi * 196 + col) * 256 + m] = pack;
        }
    }
}

// ---------------- bf16 MFMA deconv: M=1024 (o*4+d), K=256, out f32 NCHW 28x28 ----------------
__global__ __launch_bounds__(256) void deconv_mfma_k(const ushort_t* __restrict__ Wb,
        const ushort_t* __restrict__ In, const float* __restrict__ bias,
        float* __restrict__ Out, int NC) {
    __shared__ __align__(16) ushort_t As[2048];
    __shared__ __align__(16) ushort_t Bs[2048];
    int t = threadIdx.x;
    int wave = t >> 6, lane = t & 63;
    int wm = wave >> 1, wn = wave & 1;
    int m0 = blockIdx.y * 64, n0 = blockIdx.x * 64;
    f4v acc[2][2] = {};
    int arow = t >> 2, akseg = t & 3;
    int bcol = t & 63, bkseg = t >> 6;
    int colg = n0 + bcol;
    bool colok = colg < NC;
    int rl = lane & 15, kseg = lane >> 4;

    for (int k0 = 0; k0 < 256; k0 += 32) {
        {
            int idx = arow * 32 + akseg * 8;
            int sidx = idx ^ (((idx >> 6) & 3) << 3);
            *(s8v*)&As[sidx] = *(const s8v*)&Wb[(size_t)(m0 + arow) * 256 + k0 + akseg * 8];
        }
        {
            s8v v = {0, 0, 0, 0, 0, 0, 0, 0};
            if (colok)
                v = *(const s8v*)&In[(size_t)colg * 256 + k0 + bkseg * 8];
            int idx = bcol * 32 + bkseg * 8;
            int sidx = idx ^ (((idx >> 6) & 3) << 3);
            *(s8v*)&Bs[sidx] = v;
        }
        __syncthreads();
        s8v a[2], b[2];
#pragma unroll
        for (int i = 0; i < 2; i++) {
            int row = wm * 32 + i * 16 + rl;
            int idx = row * 32 + kseg * 8;
            idx ^= ((idx >> 6) & 3) << 3;
            a[i] = *(const s8v*)&As[idx];
        }
#pragma unroll
        for (int j = 0; j < 2; j++) {
            int col = wn * 32 + j * 16 + rl;
            int idx = col * 32 + kseg * 8;
            idx ^= ((idx >> 6) & 3) << 3;
            b[j] = *(const s8v*)&Bs[idx];
        }
#pragma unroll
        for (int i = 0; i < 2; i++)
#pragma unroll
            for (int j = 0; j < 2; j++)
                acc[i][j] = MFMA16(a[i], b[j], acc[i][j]);
        __syncthreads();
    }
    int rq = lane >> 4;
#pragma unroll
    for (int i = 0; i < 2; i++) {
#pragma unroll
        for (int j = 0; j < 2; j++) {
            int col = n0 + wn * 32 + j * 16 + rl;
            if (col >= NC) continue;
            int n = col / 196;
            int p = col - n * 196;
            int y = p / 14, x = p - y * 14;
            int m = m0 + wm * 32 + i * 16 + rq * 4;
            int o = m >> 2;
            float bv = bias[o];
            float2 lo, hi;
            lo.x = fmaxf(acc[i][j][0] + bv, 0.0f);
            lo.y = fmaxf(acc[i][j][1] + bv, 0.0f);
            hi.x = fmaxf(acc[i][j][2] + bv, 0.0f);
            hi.y = fmaxf(acc[i][j][3] + bv, 0.0f);
            size_t base = ((size_t)n * 256 + o) * 784;
            *(float2*)&Out[base + (size_t)(2 * y) * 28 + 2 * x] = lo;
            *(float2*)&Out[base + (size_t)(2 * y + 1) * 28 + 2 * x] = hi;
        }
    }
}

// ---------------- softmax over 81 + box decode for classes 1..80 ----------------
__global__ __launch_bounds__(128) void softmax_decode_k(const float* __restrict__ logits,
        const float* __restrict__ reg, const float* __restrict__ bbox,
        float* __restrict__ scores_c, float* __restrict__ boxes_c) {
    int n = blockIdx.x, t = threadIdx.x;
    __shared__ float sl[81];
    __shared__ float red[128];
    if (t < 81) sl[t] = logits[n * 81 + t];
    __syncthreads();
    red[t] = (t < 81) ? sl[t] : -3.0e38f;
    __syncthreads();
    for (int s = 64; s > 0; s >>= 1) { if (t < s) red[t] = fmaxf(red[t], red[t + s]); __syncthreads(); }
    float mx = red[0];
    __syncthreads();
    float e = (t < 81) ? expf(sl[t] - mx) : 0.0f;
    red[t] = e;
    __syncthreads();
    for (int s = 64; s > 0; s >>= 1) { if (t < s) red[t] += red[t + s]; __syncthreads(); }
    float sum = red[0];
    if (t >= 1 && t < 81) {
        float score = e / sum;
        float bx1 = bbox[n * 4 + 0], by1 = bbox[n * 4 + 1];
        float bx2 = bbox[n * 4 + 2], by2 = bbox[n * 4 + 3];
        float w = bx2 - bx1 + 1.0f, h = by2 - by1 + 1.0f;
        float cx = bx1 + 0.5f * w, cy = by1 + 0.5f * h;
        const float* dn = reg + (size_t)n * 324 + t * 4;
        float dx = dn[0] / 10.0f;
        float dy = dn[1] / 10.0f;
        float dw = fminf(dn[2] / 5.0f, CLAMPV);
        float dh = fminf(dn[3] / 5.0f, CLAMPV);
        float pcx = dx * w + cx, pcy = dy * h + cy;
        float pw = expf(dw) * w, ph = expf(dh) * h;
        float x1 = fminf(fmaxf(pcx - 0.5f * pw, 0.0f), 799.0f);
        float y1 = fminf(fmaxf(pcy - 0.5f * ph, 0.0f), 799.0f);
        float x2 = fminf(fmaxf(pcx + 0.5f * pw - 1.0f, 0.0f), 799.0f);
        float y2 = fminf(fmaxf(pcy + 0.5f * ph - 1.0f, 0.0f), 799.0f);
        int cc = t - 1;
        scores_c[cc * 512 + n] = score;
        float* bo = boxes_c + ((size_t)cc * 512 + n) * 4;
        bo[0] = x1; bo[1] = y1; bo[2] = x2; bo[3] = y2;
    }
}

// ---------------- per-class NMS, score-filtered; compact candidate append ----------------
__global__ __launch_bounds__(256) void nms_k(const float* __restrict__ scores_c,
        const float* __restrict__ boxes_c, u64* __restrict__ cand, int* __restrict__ cnt) {
    int c = blockIdx.x, t = threadIdx.x;
    int lane = t & 63, wave = t >> 6;
    __shared__ float s[512];
    __shared__ float fs[512];
    __shared__ short fidx[512];
    __shared__ float4 ob[512];
    __shared__ short sidx[512];
    __shared__ u64 mask[512][8];
    __shared__ u64 remw[8];
    __shared__ unsigned char stat[512];
    __shared__ int mcnt;
    if (t == 0) mcnt = 0;
    for (int i = t; i < 512; i += 256) {
        s[i] = scores_c[c * 512 + i];
        stat[i] = 0;
    }
    __syncthreads();
    for (int i = t; i < 512; i += 256) {
        if (s[i] > SCORE_THR) {
            int p = atomicAdd(&mcnt, 1);
            fs[p] = s[i];
            fidx[p] = (short)i;
        }
    }
    __syncthreads();
    int m = mcnt;
    if (m > 0) {
        for (int i = t; i < m; i += 256) {
            float si = fs[i];
            int ii = fidx[i];
            int r = 0;
            for (int j = 0; j < m; j++) {
                float sj = fs[j];
                r += (sj > si) || (sj == si && fidx[j] < ii);
            }
            sidx[r] = (short)ii;
        }
        __syncthreads();
        for (int r = t; r < m; r += 256)
            ob[r] = *(const float4*)(boxes_c + ((size_t)c * 512 + sidx[r]) * 4);
        __syncthreads();
        int W = (m + 63) >> 6;
        for (int i = wave; i < m; i += 4) {
            float4 a = ob[i];
            float aarea = (a.z - a.x + 1.0f) * (a.w - a.y + 1.0f);
            for (int b = 0; b < W; b++) {
                int j = b * 64 + lane;
                float4 bb = ob[j < m ? j : 0];
                float barea = (bb.z - bb.x + 1.0f) * (bb.w - bb.y + 1.0f);
                float lx = fmaxf(a.x, bb.x), lyv = fmaxf(a.y, bb.y);
                float rx = fminf(a.z, bb.z), ry = fminf(a.w, bb.w);
                float iw = fmaxf(rx - lx + 1.0f, 0.0f);
                float ih = fmaxf(ry - lyv + 1.0f, 0.0f);
                float inter = iw * ih;
                float iou = inter / (aarea + barea - inter);
                u64 bal = __ballot((j < m) && (j > i) && (iou > NMS_THR));
                if (lane == 0) mask[i][b] = bal;
            }
        }
        __syncthreads();
        if (wave == 0) {
            u64 rm = 0;
            for (int i = 0; i < m; i++) {
                u64 w = shfl64(rm, i >> 6);
                if (!((w >> (i & 63)) & 1ull) && lane < W) rm |= mask[i][lane];
            }
            if (lane < 8) remw[lane] = rm;
        }
        __syncthreads();
        for (int r = t; r < m; r += 256) {
            bool kept = !((remw[r >> 6] >> (r & 63)) & 1ull);
            if (kept) stat[sidx[r]] = 1;
        }
        __syncthreads();
    }
    // append: all positives, plus class-0 flats 0..199 as the -1.0 pad pool.
    for (int i = t; i < 512; i += 256) {
        float val = stat[i] ? s[i] : -1.0f;
        if ((c == 0 && i < 200) || val != -1.0f) {
            int flat = c * 512 + i;
            u32 u = __float_as_uint(val);
            u = (u & 0x80000000u) ? ~u : (u | 0x80000000u);
            u64 key = ((u64)u << 32) | (u64)(0xFFFFFFFFu - (u32)flat);
            int pos = atomicAdd(cnt, 1);
            cand[pos] = key;
        }
    }
}

// ---------------- top-100 via parallel rank selection (keys strictly unique) ----------------
#define TCAP 8192
#define TCHUNK (TCAP - 128)
__global__ __launch_bounds__(512) void topk3_k(const u64* __restrict__ cand,
        const int* __restrict__ cnt, const float* __restrict__ boxes_c,
        float* __restrict__ out) {
    __shared__ u64 ck[TCAP];
    __shared__ u64 wk[100];
    int t = threadIdx.x;
    int n = *cnt;
    for (int i = t; i < 100; i += 512) wk[i] = 0;
    __syncthreads();
    for (int base = 0; base < n; base += TCHUNK) {
        int sz = min(n - base, TCHUNK);
        for (int i = t; i < 100; i += 512) ck[i] = wk[i];
        for (int i = t; i < sz; i += 512) ck[100 + i] = cand[base + i];
        int tot = 100 + sz;
        __syncthreads();
        for (int i = t; i < tot; i += 512) {
            u64 ki = ck[i];
            int r = 0;
            for (int j = 0; j < tot; j++) {
                u64 kj = ck[j];
                r += (kj > ki) || (kj == ki && j < i);
                if (r >= 100) break;
            }
            if (r < 100) wk[r] = ki;
        }
        __syncthreads();
    }
    if (t < 100) {
        u64 bk = wk[t];
        u32 flat = 0xFFFFFFFFu - (u32)(bk & 0xFFFFFFFFull);
        u32 u = (u32)(bk >> 32);
        float val = (u & 0x80000000u) ? __uint_as_float(u & 0x7FFFFFFFu)
                                      : __uint_as_float(~u);
        int cls = (int)(flat >> 9);
        out[t * 4 + 0] = boxes_c[(size_t)flat * 4 + 0];
        out[t * 4 + 1] = boxes_c[(size_t)flat * 4 + 1];
        out[t * 4 + 2] = boxes_c[(size_t)flat * 4 + 2];
        out[t * 4 + 3] = boxes_c[(size_t)flat * 4 + 3];
        out[400 + t] = (float)(cls + 1);
        out[78900 + t] = fmaxf(val, 0.0f);
    }
}

// ---------------- mask head stage 1: partial dot over 32 channels ----------------
__global__ __launch_bounds__(256) void mask_part_k(const float* __restrict__ D,
        const float* __restrict__ w2, const float* __restrict__ out,
        float* __restrict__ MP) {
    int n = blockIdx.x, q = blockIdx.y, t = threadIdx.x;
    int lab = (int)(out[400 + n] + 0.5f);
    __shared__ float wsh[32];
    if (t < 32) wsh[t] = w2[lab * 256 + q * 32 + t];
    __syncthreads();
    const float* Dn = D + (size_t)n * 256 * 784 + (size_t)q * 32 * 784;
    float a0 = 0.0f, a1 = 0.0f, a2 = 0.0f, a3 = 0.0f;
    for (int o = 0; o < 32; o++) {
        float wv = wsh[o];
        const float* Dp = Dn + o * 784;
        a0 += Dp[t] * wv;
        a1 += Dp[t + 256] * wv;
        a2 += Dp[t + 512] * wv;
        if (t < 16) a3 += Dp[t + 768] * wv;
    }
    float* mp = MP + ((size_t)n * 8 + q) * 784;
    mp[t] = a0;
    mp[t + 256] = a1;
    mp[t + 512] = a2;
    if (t < 16) mp[t + 768] = a3;
}

// ---------------- mask head stage 2: sum 8 partials + bias + sigmoid ----------------
__global__ __launch_bounds__(256) void mask_fin_k(const float* __restrict__ MP,
        const float* __restrict__ b2, float* __restrict__ out) {
    int n = blockIdx.x, t = threadIdx.x;
    int lab = (int)(out[400 + n] + 0.5f);
    float bb = b2[lab];
    const float* mp = MP + (size_t)n * 8 * 784;
    for (int p = t; p < 784; p += 256) {
        float s = 0.0f;
#pragma unroll
        for (int q = 0; q < 8; q++) s += mp[q * 784 + p];
        s += bb;
        out[500 + n * 784 + p] = 1.0f / (1.0f + expf(-s));
    }
}

extern "C" void kernel_launch(void* const* d_in, const int* in_sizes, int n_in,
                              void* d_out, int out_size, void* d_ws, size_t ws_size,
                              hipStream_t stream) {
    const float* features = (const float*)d_in[0];
    const float* bbox = (const float*)d_in[1];
    const float* fc1_w = (const float*)d_in[3];
    const float* fc1_b = (const float*)d_in[4];
    const float* fc2_w = (const float*)d_in[5];
    const float* fc2_b = (const float*)d_in[6];
    const float* cls_w = (const float*)d_in[7];
    const float* cls_b = (const float*)d_in[8];
    const float* reg_w = (const float*)d_in[9];
    const float* reg_b = (const float*)d_in[10];
    const float* mc1w = (const float*)d_in[11];
    const float* mc1b = (const float*)d_in[12];
    const float* mc2w = (const float*)d_in[13];
    const float* mc2b = (const float*)d_in[14];
    const float* mc3w = (const float*)d_in[15];
    const float* mc3b = (const float*)d_in[16];
    const float* mc4w = (const float*)d_in[17];
    const float* mc4b = (const float*)d_in[18];
    const float* dcw = (const float*)d_in[19];
    const float* dcb = (const float*)d_in[20];
    const float* mpw = (const float*)d_in[21];
    const float* mpb = (const float*)d_in[22];
    float* out = (float*)d_out;
    float* ws = (float*)d_ws;

    // ---- workspace layout (float offsets), time-multiplexed ----
    // R14: GEMM partials moved to [20,070,400 .. 24,264,704) — dead during
    // the whole detect phase (Abf/Bbf are mask-phase-only, W1b+ start at
    // 25.09M, CAND/CNT end below 19.68M). FEAT at ws+0 therefore survives
    // until roi_align_mask_k -> the second transpose is DELETED
    // unconditionally. D (deconv out) overlays ws+0 only after
    // roi_align_mask_k consumed FEAT. Peak ws unchanged.
    float* FEAT = ws + 0;
    float* D    = ws + 0;                         // mask phase (deconv out)
    ushort_t* XFh = (ushort_t*)(ws + 10240000);
    ushort_t* XFl = (ushort_t*)(ws + 13451264);
    ushort_t* W1h = (ushort_t*)(ws + 16662528);
    ushort_t* W1l = (ushort_t*)(ws + 23085056);   // [.. 29,507,584)
    ushort_t* H1h = (ushort_t*)(ws + 16662528);
    ushort_t* H1l = (ushort_t*)(ws + 16924672);
    ushort_t* H2h = (ushort_t*)(ws + 17186816);
    ushort_t* H2l = (ushort_t*)(ws + 17448960);
    ushort_t* W2h = (ushort_t*)(ws + 17711104);
    ushort_t* W2l = (ushort_t*)(ws + 18235392);
    ushort_t* Wcrh = (ushort_t*)(ws + 18759680);
    ushort_t* Wcrl = (ushort_t*)(ws + 18967040);
    float* LOGI = ws + 19174400;
    float* REG  = ws + 19215872;
    float* BXC  = ws + 19381760;
    float* SCC  = ws + 19545600;
    u64*  CAND  = (u64*)(ws + 19586560);
    int*  CNT   = (int*)(ws + 19670000);
    float* PARTg = ws + 20070400;                 // detect phase, 4.19M floats
    ushort_t* Abf = (ushort_t*)(ws + 20070400);   // mask phase (over dead PART)
    ushort_t* Bbf = (ushort_t*)(ws + 22579200);
    ushort_t* W1b = (ushort_t*)(ws + 25088000);
    ushort_t* W2b = (ushort_t*)(ws + 25382912);
    ushort_t* W3b = (ushort_t*)(ws + 25677824);
    ushort_t* W4b = (ushort_t*)(ws + 25972736);
    ushort_t* WDb = (ushort_t*)(ws + 26267648);   // ends 26,398,720
    float* MP   = ws + 26398720;

    transpose_k<<<dim3(1250, 8), dim3(32, 8), 0, stream>>>(features, FEAT, 256, 40000);
    cvt_w1_k<<<1024, 256, 0, stream>>>(fc1_w, W1h, W1l);
    roi_align_hilo_k<<<dim3(49, 512), 256, 0, stream>>>(FEAT, bbox, XFh, XFl);

    // fc1: 128x128-tile K-blocked double-buffered kernel, XCD-aware grid:
    // launched (z, x, y) so the K-chunk is the fastest dim -> one XCD per chunk.
    gemm128_k<<<dim3(8, 8, 4), 512, 0, stream>>>(XFh, XFl, W1h, W1l, PARTg, 512, 1024, 392, 49);
    reduce2_k<<<2048, 256, 0, stream>>>(PARTg, fc1_b, (float*)nullptr, H1h, H1l, 512, 1024, 8, 1);

    cvt_hilo3_k<<<5716, 256, 0, stream>>>(fc2_w, cls_w, reg_w, W2h, W2l,
            Wcrh, Wcrl, Wcrh + 81 * 1024, Wcrl + 81 * 1024);
    cvt_allw_k<<<10240, 256, 0, stream>>>(mc1w, mc2w, mc3w, mc4w, dcw, W1b, W2b, W3b, W4b, WDb, CNT);

    gemm3_mfma_k<<<dim3(16, 8, 8), 256, 0, stream>>>(H1h, H1l, W2h, W2l, PARTg, 512, 1024, 1024, 128);
    reduce2_k<<<2048, 256, 0, stream>>>(PARTg, fc2_b, (float*)nullptr, H2h, H2l, 512, 1024, 8, 1);
    gemm3_mfma_k<<<dim3(7, 8, 8), 256, 0, stream>>>(H2h, H2l, Wcrh, Wcrl, PARTg, 512, 405, 1024, 128);
    reduce_cr_k<<<810, 256, 0, stream>>>(PARTg, cls_b, reg_b, LOGI, REG);
    // PARTg dead from here.

    softmax_decode_k<<<512, 128, 0, stream>>>(LOGI, REG, bbox, SCC, BXC);
    nms_k<<<80, 256, 0, stream>>>(SCC, BXC, CAND, CNT);
    topk3_k<<<1, 512, 0, stream>>>(CAND, CNT, BXC, out);

    // mask branch: FEAT still intact (no second transpose needed)
    roi_align_mask_k<<<dim3(196, 100), 256, 0, stream>>>(FEAT, out, Abf);
    conv3_roi_k<<<416, 256, 0, stream>>>(W1b, Abf, mc1b, Bbf);
    conv3_roi_k<<<416, 256, 0, stream>>>(W2b, Bbf, mc2b, Abf);
    conv3_roi_k<<<416, 256, 0, stream>>>(W3b, Abf, mc3b, Bbf);
    conv3_roi_k<<<416, 256, 0, stream>>>(W4b, Bbf, mc4b, Abf);
    deconv_mfma_k<<<dim3(307, 16), 256, 0, stream>>>(WDb, Abf, dcb, D, 19600);
    mask_part_k<<<dim3(100, 8), 256, 0, stream>>>(D, mpw, out, MP);
    mask_fin_k<<<100, 256, 0, stream>>>(MP, mpb, out);
}

// Round 15
// 457.726 us; speedup vs baseline: 1.0211x; 1.0048x over previous
//
#include <hip/hip_runtime.h>
#include <cstdint>
#include <cstddef>

typedef unsigned long long u64;
typedef unsigned int u32;
typedef unsigned short ushort_t;
typedef __attribute__((ext_vector_type(8))) short s8v;
typedef __attribute__((ext_vector_type(4))) float f4v;

#define NMS_THR 0.5f
#define SCORE_THR 0.05f
#define CLAMPV 4.135166556742356f
#define MFMA16(a,b,c) __builtin_amdgcn_mfma_f32_16x16x32_bf16(a,b,c,0,0,0)

static __device__ inline ushort_t f2b(float f) {
    u32 u = __float_as_uint(f);
    return (ushort_t)((u + 0x7FFFu + ((u >> 16) & 1u)) >> 16);
}
static __device__ inline float b2f(ushort_t h) {
    return __uint_as_float((u32)h << 16);
}
static __device__ inline u64 shfl64(u64 v, int src) {
    int lo = __shfl((int)(u32)v, src, 64);
    int hi = __shfl((int)(u32)(v >> 32), src, 64);
    return ((u64)(u32)hi << 32) | (u64)(u32)lo;
}
// direct global->LDS DMA, 16B per lane. LDS dest is wave-uniform base + lane*16.
static __device__ __forceinline__ void gload16(const void* g, void* l) {
    __builtin_amdgcn_global_load_lds(
        (const __attribute__((address_space(1))) void*)g,
        (__attribute__((address_space(3))) void*)l, 16, 0, 0);
}

// ---------------- transpose (rows, cols) -> (cols, rows) ----------------
__global__ __launch_bounds__(256) void transpose_k(const float* __restrict__ in,
        float* __restrict__ out, int rows, int cols) {
    __shared__ float tile[32][33];
    int c0 = blockIdx.x * 32, r0 = blockIdx.y * 32;
    int tx = threadIdx.x, ty = threadIdx.y;
#pragma unroll
    for (int i = 0; i < 32; i += 8) {
        int r = r0 + ty + i, c = c0 + tx;
        if (r < rows && c < cols) tile[ty + i][tx] = in[(size_t)r * cols + c];
    }
    __syncthreads();
#pragma unroll
    for (int i = 0; i < 32; i += 8) {
        int r = c0 + ty + i, c = r0 + tx;
        if (r < cols && c < rows) out[(size_t)r * rows + c] = tile[tx][ty + i];
    }
}

// ---------------- weight converts ----------------
// fc1 weight in K-BLOCKED layout: [panel p=o>>7][kstep=k'>>5][row=o&127][32].
__global__ __launch_bounds__(256) void cvt_w1_k(const float* __restrict__ w,
        ushort_t* __restrict__ Wh, ushort_t* __restrict__ Wl) {
    __shared__ float row[12544];
    int o = blockIdx.x;
    const float* src = w + (size_t)o * 12544;
    for (int i = threadIdx.x; i < 12544; i += 256) row[i] = src[i];
    __syncthreads();
    int p = o >> 7, r = o & 127;
    for (int i = threadIdx.x; i < 12544; i += 256) {
        int s = i >> 8, c = i & 255;
        float v = row[c * 49 + s];
        ushort_t h = f2b(v);
        ushort_t l = f2b(v - b2f(h));
        size_t idx = ((size_t)(p * 392 + (i >> 5)) << 12) + (r << 5) + (i & 31);
        Wh[idx] = h;
        Wl[idx] = l;
    }
}

// fused hi/lo split for fc2 (1048576) + cls (82944) + reg (331776)
__global__ __launch_bounds__(256) void cvt_hilo3_k(const float* __restrict__ w2,
        const float* __restrict__ wc, const float* __restrict__ wr,
        ushort_t* __restrict__ h2, ushort_t* __restrict__ l2,
        ushort_t* __restrict__ hc, ushort_t* __restrict__ lc,
        ushort_t* __restrict__ hr, ushort_t* __restrict__ lr) {
    int i = blockIdx.x * 256 + threadIdx.x;
    const float* w; ushort_t* h; ushort_t* l; int r;
    if (i < 1048576) { w = w2; h = h2; l = l2; r = i; }
    else if (i < 1131520) { w = wc; h = hc; l = lc; r = i - 1048576; }
    else if (i < 1463296) { w = wr; h = hr; l = lr; r = i - 1131520; }
    else return;
    float v = w[r];
    ushort_t hh = f2b(v);
    h[r] = hh;
    l[r] = f2b(v - b2f(hh));
}

// fused conv weights (4 x 589824) + deconv (262144) convert; also zeroes CNT
__global__ __launch_bounds__(256) void cvt_allw_k(const float* __restrict__ w1,
        const float* __restrict__ w2, const float* __restrict__ w3,
        const float* __restrict__ w4, const float* __restrict__ wd,
        ushort_t* __restrict__ o1, ushort_t* __restrict__ o2,
        ushort_t* __restrict__ o3, ushort_t* __restrict__ o4,
        ushort_t* __restrict__ od, int* __restrict__ cnt) {
    int t = blockIdx.x * 256 + threadIdx.x;
    if (t == 0) *cnt = 0;
    if (t < 2359296) {
        int which = t / 589824;
        int r = t - which * 589824;
        const float* w = (which == 0) ? w1 : (which == 1) ? w2 : (which == 2) ? w3 : w4;
        ushort_t* o = (which == 0) ? o1 : (which == 1) ? o2 : (which == 2) ? o3 : o4;
        int oc = r / 2304;
        int rem = r - oc * 2304;
        int kk = rem >> 8;
        int ci = rem & 255;
        o[r] = f2b(w[oc * 2304 + ci * 9 + kk]);
    } else {
        int r = t - 2359296;
        if (r < 262144) {
            int m = r >> 8;
            int ci = r & 255;
            od[r] = f2b(wd[ci * 1024 + m]);
        }
    }
}

// ---------------- roi align (FC path): hi/lo bf16 out, K-blocked layout ----------------
__global__ __launch_bounds__(256) void roi_align_hilo_k(const float* __restrict__ feat,
        const float* __restrict__ rois, ushort_t* __restrict__ outh,
        ushort_t* __restrict__ outl) {
    int c = threadIdx.x;
    int s = blockIdx.x;
    int n = blockIdx.y;
    const int P = 7;
    int py = s / P, px = s - py * P;
    float rx1 = rois[n * 4 + 0] * 0.25f;
    float ry1 = rois[n * 4 + 1] * 0.25f;
    float rx2 = rois[n * 4 + 2] * 0.25f;
    float ry2 = rois[n * 4 + 3] * 0.25f;
    float bw = fmaxf(rx2 - rx1, 1.0f) / (float)P;
    float bh = fmaxf(ry2 - ry1, 1.0f) / (float)P;
    float acc = 0.0f;
#pragma unroll
    for (int sy = 0; sy < 2; sy++)
#pragma unroll
        for (int sx = 0; sx < 2; sx++) {
            float y = ry1 + ((float)py + ((float)sy + 0.5f) * 0.5f) * bh;
            float x = rx1 + ((float)px + ((float)sx + 0.5f) * 0.5f) * bw;
            y = fminf(fmaxf(y, 0.0f), 199.0f);
            x = fminf(fmaxf(x, 0.0f), 199.0f);
            float y0f = floorf(y), x0f = floorf(x);
            float ly = y - y0f, lx = x - x0f;
            int y0 = (int)y0f, x0 = (int)x0f;
            int y1 = min(y0 + 1, 199), x1 = min(x0 + 1, 199);
            float v00 = feat[((size_t)(y0 * 200 + x0)) * 256 + c];
            float v01 = feat[((size_t)(y0 * 200 + x1)) * 256 + c];
            float v10 = feat[((size_t)(y1 * 200 + x0)) * 256 + c];
            float v11 = feat[((size_t)(y1 * 200 + x1)) * 256 + c];
            acc += v00 * (1.0f - ly) * (1.0f - lx) + v01 * (1.0f - ly) * lx
                 + v10 * ly * (1.0f - lx) + v11 * ly * lx;
        }
    float v = acc * 0.25f;
    ushort_t h = f2b(v);
    int kp = s * 256 + c;                       // k' index
    size_t idx = ((size_t)((n >> 7) * 392 + (kp >> 5)) << 12)
               + ((n & 127) << 5) + (kp & 31);
    outh[idx] = h;
    outl[idx] = f2b(v - b2f(h));
}

// ---------------- roi align (mask path), bf16 channels-last out ----------------
__global__ __launch_bounds__(256) void roi_align_mask_k(const float* __restrict__ feat,
        const float* __restrict__ dets, ushort_t* __restrict__ out) {
    int c = threadIdx.x;
    int s = blockIdx.x;
    int n = blockIdx.y;
    const int P = 14;
    int py = s / P, px = s - py * P;
    float rx1 = dets[n * 4 + 0] * 0.25f;
    float ry1 = dets[n * 4 + 1] * 0.25f;
    float rx2 = dets[n * 4 + 2] * 0.25f;
    float ry2 = dets[n * 4 + 3] * 0.25f;
    float bw = fmaxf(rx2 - rx1, 1.0f) / (float)P;
    float bh = fmaxf(ry2 - ry1, 1.0f) / (float)P;
    float acc = 0.0f;
#pragma unroll
    for (int sy = 0; sy < 2; sy++)
#pragma unroll
        for (int sx = 0; sx < 2; sx++) {
            float y = ry1 + ((float)py + ((float)sy + 0.5f) * 0.5f) * bh;
            float x = rx1 + ((float)px + ((float)sx + 0.5f) * 0.5f) * bw;
            y = fminf(fmaxf(y, 0.0f), 199.0f);
            x = fminf(fmaxf(x, 0.0f), 199.0f);
            float y0f = floorf(y), x0f = floorf(x);
            float ly = y - y0f, lx = x - x0f;
            int y0 = (int)y0f, x0 = (int)x0f;
            int y1 = min(y0 + 1, 199), x1 = min(x0 + 1, 199);
            float v00 = feat[((size_t)(y0 * 200 + x0)) * 256 + c];
            float v01 = feat[((size_t)(y0 * 200 + x1)) * 256 + c];
            float v10 = feat[((size_t)(y1 * 200 + x0)) * 256 + c];
            float v11 = feat[((size_t)(y1 * 200 + x1)) * 256 + c];
            acc += v00 * (1.0f - ly) * (1.0f - lx) + v01 * (1.0f - ly) * lx
                 + v10 * ly * (1.0f - lx) + v11 * ly * lx;
        }
    out[((size_t)n * 196 + s) * 256 + c] = f2b(acc * 0.25f);
}

// ---------------- error-compensated bf16 MFMA split-K GEMM (64-tile) ----------------
// (kept for fc2 / cls+reg; fc1 uses gemm128_k below)
__global__ __launch_bounds__(256) void gemm3_mfma_k(const ushort_t* __restrict__ Ah,
        const ushort_t* __restrict__ Al, const ushort_t* __restrict__ Bh,
        const ushort_t* __restrict__ Bl, float* __restrict__ P,
        int M, int N, int K, int kchunk) {
    __shared__ __align__(16) ushort_t AsH[2048], AsL[2048], BsH[2048], BsL[2048];
    int t = threadIdx.x;
    int wave = t >> 6, lane = t & 63;
    int wm = wave >> 1, wn = wave & 1;
    int m0 = blockIdx.y * 64, n0 = blockIdx.x * 64;
    int z = blockIdx.z;
    int kb = z * kchunk, ke = min(K, kb + kchunk);
    f4v acc[2][2] = {};
    int rl = lane & 15, kseg = lane >> 4;
    // source pre-swizzle: LDS granule t holds global granule t^((t>>3)&3)
    int gsw = t ^ ((t >> 3) & 3);
    int grow = gsw >> 2, gseg = gsw & 3;
    size_t aoff = (size_t)(m0 + grow) * K + gseg * 8;
    size_t boff = (size_t)(n0 + grow) * K + gseg * 8;
    for (int k0 = kb; k0 < ke; k0 += 32) {
        gload16(&Ah[aoff + k0], &AsH[t * 8]);
        gload16(&Al[aoff + k0], &AsL[t * 8]);
        gload16(&Bh[boff + k0], &BsH[t * 8]);
        gload16(&Bl[boff + k0], &BsL[t * 8]);
        __syncthreads();
        s8v ah[2], al[2], bh[2], bl[2];
#pragma unroll
        for (int i = 0; i < 2; i++) {
            int row = wm * 32 + i * 16 + rl;
            int idx = row * 32 + kseg * 8;
            idx ^= ((idx >> 6) & 3) << 3;
            ah[i] = *(const s8v*)&AsH[idx];
            al[i] = *(const s8v*)&AsL[idx];
        }
#pragma unroll
        for (int j = 0; j < 2; j++) {
            int col = wn * 32 + j * 16 + rl;
            int idx = col * 32 + kseg * 8;
            idx ^= ((idx >> 6) & 3) << 3;
            bh[j] = *(const s8v*)&BsH[idx];
            bl[j] = *(const s8v*)&BsL[idx];
        }
#pragma unroll
        for (int i = 0; i < 2; i++)
#pragma unroll
            for (int j = 0; j < 2; j++) {
                acc[i][j] = MFMA16(al[i], bh[j], acc[i][j]);
                acc[i][j] = MFMA16(ah[i], bl[j], acc[i][j]);
                acc[i][j] = MFMA16(ah[i], bh[j], acc[i][j]);
            }
        __syncthreads();
    }
    float* Pz = P + (size_t)z * M * N;
    int rq = lane >> 4;
#pragma unroll
    for (int i = 0; i < 2; i++) {
#pragma unroll
        for (int j = 0; j < 2; j++) {
            int col = n0 + wn * 32 + j * 16 + rl;
            if (col >= N) continue;
            int m = m0 + wm * 32 + i * 16 + rq * 4;
#pragma unroll
            for (int r = 0; r < 4; r++)
                Pz[(size_t)(m + r) * N + col] = acc[i][j][r];
        }
    }
}

// ---------------- 128x128-tile hi/lo GEMM for fc1, K-blocked operands ----------------
// R12-proven 2-buffer pipeline; XCD-aware grid (z fastest); K-blocked
// operands (8KB contiguous tiles). At its structural ceiling (R13 falsified
// deeper pipelining).
__global__ __launch_bounds__(512) void gemm128_k(const ushort_t* __restrict__ Ah,
        const ushort_t* __restrict__ Al, const ushort_t* __restrict__ Bh,
        const ushort_t* __restrict__ Bl, float* __restrict__ P,
        int M, int N, int nsteps_total, int chunk_steps) {
    __shared__ __align__(16) ushort_t AsH[2][4096], AsL[2][4096], BsH[2][4096], BsL[2][4096];
    int t = threadIdx.x;
    int wave = t >> 6, lane = t & 63;
    int wm = wave >> 2, wn = wave & 3;          // 2 x 4 wave grid, wave = 64x32
    // grid remap: launched as (z, x, y) so z is fastest -> z maps to XCD
    int z  = blockIdx.x;
    int xb = blockIdx.y;                        // N-block
    int yb = blockIdx.z;                        // M-block
    int sb = z * chunk_steps, se = min(nsteps_total, sb + chunk_steps);
    f4v acc[4][2] = {};
    int rl = lane & 15, kseg = lane >> 4;
    // source pre-swizzle: LDS granule t holds global granule t^((t>>3)&3)
    int gsw = t ^ ((t >> 3) & 3);
    size_t abase = ((size_t)yb * nsteps_total) << 12;
    size_t bbase = ((size_t)xb * nsteps_total) << 12;
    int goff = gsw * 8;
    // prologue: stage step sb into buf 0
    gload16(&Ah[abase + ((size_t)sb << 12) + goff], &AsH[0][t * 8]);
    gload16(&Al[abase + ((size_t)sb << 12) + goff], &AsL[0][t * 8]);
    gload16(&Bh[bbase + ((size_t)sb << 12) + goff], &BsH[0][t * 8]);
    gload16(&Bl[bbase + ((size_t)sb << 12) + goff], &BsL[0][t * 8]);
    __syncthreads();
    int cur = 0;
    for (int ks = sb; ks < se; ks++) {
        if (ks + 1 < se) {
            size_t o = ((size_t)(ks + 1) << 12) + goff;
            gload16(&Ah[abase + o], &AsH[cur ^ 1][t * 8]);
            gload16(&Al[abase + o], &AsL[cur ^ 1][t * 8]);
            gload16(&Bh[bbase + o], &BsH[cur ^ 1][t * 8]);
            gload16(&Bl[bbase + o], &BsL[cur ^ 1][t * 8]);
        }
        s8v ah[4], al[4], bh[2], bl[2];
#pragma unroll
        for (int i = 0; i < 4; i++) {
            int row = wm * 64 + i * 16 + rl;
            int idx = row * 32 + kseg * 8;
            idx ^= ((idx >> 6) & 3) << 3;
            ah[i] = *(const s8v*)&AsH[cur][idx];
            al[i] = *(const s8v*)&AsL[cur][idx];
        }
#pragma unroll
        for (int j = 0; j < 2; j++) {
            int col = wn * 32 + j * 16 + rl;
            int idx = col * 32 + kseg * 8;
            idx ^= ((idx >> 6) & 3) << 3;
            bh[j] = *(const s8v*)&BsH[cur][idx];
            bl[j] = *(const s8v*)&BsL[cur][idx];
        }
#pragma unroll
        for (int i = 0; i < 4; i++)
#pragma unroll
            for (int j = 0; j < 2; j++) {
                acc[i][j] = MFMA16(al[i], bh[j], acc[i][j]);
                acc[i][j] = MFMA16(ah[i], bl[j], acc[i][j]);
                acc[i][j] = MFMA16(ah[i], bh[j], acc[i][j]);
            }
        __syncthreads();
        cur ^= 1;
    }
    float* Pz = P + (size_t)z * M * N;
    int rq = lane >> 4;
    int m0 = yb * 128, n0 = xb * 128;
#pragma unroll
    for (int i = 0; i < 4; i++) {
#pragma unroll
        for (int j = 0; j < 2; j++) {
            int col = n0 + wn * 32 + j * 16 + rl;
            if (col >= N) continue;
            int m = m0 + wm * 64 + i * 16 + rq * 4;
#pragma unroll
            for (int r = 0; r < 4; r++)
                Pz[(size_t)(m + r) * N + col] = acc[i][j][r];
        }
    }
}

// reduce split-K partials + bias (+relu); write f32 and/or hi+lo bf16
__global__ __launch_bounds__(256) void reduce2_k(const float* __restrict__ P,
        const float* __restrict__ bias, float* __restrict__ Cf,
        ushort_t* __restrict__ Ch, ushort_t* __restrict__ Cl,
        int M, int N, int nsplit, int relu) {
    int idx = blockIdx.x * 256 + threadIdx.x;
    if (idx >= M * N) return;
    int n = idx % N;
    float s = 0.0f;
    for (int z = 0; z < nsplit; z++) s += P[(size_t)z * M * N + idx];
    s += bias[n];
    if (relu) s = fmaxf(s, 0.0f);
    if (Cf) Cf[idx] = s;
    if (Ch) {
        ushort_t h = f2b(s);
        Ch[idx] = h;
        Cl[idx] = f2b(s - b2f(h));
    }
}

// reduce for merged cls+reg GEMM (M=512, N=405)
__global__ __launch_bounds__(256) void reduce_cr_k(const float* __restrict__ P,
        const float* __restrict__ cls_b, const float* __restrict__ reg_b,
        float* __restrict__ LOGI, float* __restrict__ REG) {
    int idx = blockIdx.x * 256 + threadIdx.x;
    if (idx >= 512 * 405) return;
    int n = idx / 405, col = idx - n * 405;
    float s = 0.0f;
    for (int z = 0; z < 8; z++) s += P[(size_t)z * 512 * 405 + idx];
    if (col < 81) LOGI[n * 81 + col] = s + cls_b[col];
    else REG[n * 324 + (col - 81)] = s + reg_b[col - 81];
}

// ---------------- roi-resident bf16 MFMA 3x3 conv, LDS weights + global_load_lds ----------------
// R12 structure: zero-pixel sentinel (halo cndmask deleted); R8 paired
// cs-stages (K=64/stage, 36 barriers).
__global__ __launch_bounds__(256) void conv3_roi_k(const ushort_t* __restrict__ Wb,
        const ushort_t* __restrict__ In, const float* __restrict__ bias,
        ushort_t* __restrict__ Out) {
    __shared__ __align__(16) ushort_t Ibuf[200 * 128];
    __shared__ __align__(16) ushort_t Ws[2][4096];   // [buf][cs-parity*2048 + idx]
    int bid = blockIdx.x;
    int roiLow = bid & 7;
    int q = bid >> 3;
    int slice = q & 3;
    int roi = (q >> 2) * 8 + roiLow;
    if (roi >= 100) return;
    int t = threadIdx.x;
    int wave = t >> 6, lane = t & 63;
    int rl = lane & 15, kseg = lane >> 4;
    int m0 = slice * 64;
    f4v acc[4][4] = {};
    int yb[4], xb[4];
    bool cok[4];
#pragma unroll
    for (int j = 0; j < 4; j++) {
        int col = (j * 4 + wave) * 16 + rl;
        cok[j] = col < 196;
        int cc = cok[j] ? col : 0;
        yb[j] = cc / 14;
        xb[j] = cc - yb[j] * 14;
    }
    // zero sentinel pixel row 196 (persists across halves; staging only
    // writes pixels 0..195). 16 threads x 8 ushorts = 128.
    if (t < 16) {
        s8v zz = {0, 0, 0, 0, 0, 0, 0, 0};
        *(s8v*)&Ibuf[196 * 128 + t * 8] = zz;
    }
    // weight staging: LDS granule t holds global granule t^((t>>3)&3)
    int gsw = t ^ ((t >> 3) & 3);
    const ushort_t* gsrc = Wb + (size_t)(m0 + (gsw >> 2)) * 2304 + (gsw & 3) * 8;
    int cur = 0;
    for (int half = 0; half < 2; half++) {
        // Ibuf staging: granule (pix,u) sources (pix, u^(pix&7)) — linear dest
        for (int uidx = t; uidx < 3136; uidx += 256) {
            int pix = uidx >> 4, u = uidx & 15;
            int usw = u ^ (pix & 7);
            gload16(&In[(size_t)(roi * 196 + pix) * 256 + half * 128 + usw * 8],
                    &Ibuf[uidx * 8]);
        }
        if (half == 0) {  // prologue: stage (kk=0, p=0) pair into Ws[0]
            gload16(&gsrc[0], &Ws[0][t * 8]);
            gload16(&gsrc[32], &Ws[0][2048 + t * 8]);
        }
        __syncthreads();
        for (int kk = 0; kk < 9; kk++) {
            int ky = kk / 3, kx = kk - ky * 3;
            int spix[4];
#pragma unroll
            for (int j = 0; j < 4; j++) {
                int iy = yb[j] + ky - 1, ix = xb[j] + kx - 1;
                bool sval = cok[j] && iy >= 0 && iy < 14 && ix >= 0 && ix < 14;
                spix[j] = sval ? (iy * 14 + ix) : 196;   // 196 = zero sentinel
            }
#pragma unroll
            for (int p = 0; p < 2; p++) {
                int s = kk * 2 + p;               // stage index in [0,17]
                bool pf = (s < 17) || (half == 0);
                int nkbase;
                if (s < 17) {
                    int ns = s + 1;
                    nkbase = (ns >> 1) * 256 + half * 128 + (ns & 1) * 64;
                } else {
                    nkbase = 128;                 // (half=1, kk=0, p=0)
                }
                // fire-and-forget DMA prefetch of next stage's weight pair
                if (pf) {
                    gload16(&gsrc[nkbase], &Ws[cur ^ 1][t * 8]);
                    gload16(&gsrc[nkbase + 32], &Ws[cur ^ 1][2048 + t * 8]);
                }
#pragma unroll
                for (int b = 0; b < 2; b++) {
                    int cs = 2 * p + b;
                    s8v a[4], bb[4];
#pragma unroll
                    for (int i = 0; i < 4; i++) {
                        int row = i * 16 + rl;
                        int idx = row * 32 + kseg * 8;
                        idx ^= ((idx >> 6) & 3) << 3;
                        a[i] = *(const s8v*)&Ws[cur][b * 2048 + idx];
                    }
                    int u0 = cs * 4 + kseg;
#pragma unroll
                    for (int j = 0; j < 4; j++) {
                        int up = u0 ^ (spix[j] & 7);
                        bb[j] = *(const s8v*)&Ibuf[spix[j] * 128 + up * 8];
                    }
#pragma unroll
                    for (int i = 0; i < 4; i++)
#pragma unroll
                        for (int j = 0; j < 4; j++)
                            acc[i][j] = MFMA16(a[i], bb[j], acc[i][j]);
                }
                __syncthreads();
                cur ^= 1;
            }
        }
    }
    int rq = lane >> 4;
#pragma unroll
    for (int i = 0; i < 4; i++) {
        int m = m0 + i * 16 + rq * 4;
        float b0 = bias[m], b1 = bias[m + 1], b2v = bias[m + 2], b3 = bias[m + 3];
#pragma unroll
        for (int j = 0; j < 4; j++) {
            int col = (j * 4 + wave) * 16 + rl;
            if (col >= 196) continue;
            u64 pack = (u64)f2b(fmaxf(acc[i][j][0] + b0, 0.0f))
                     | ((u64)f2b(fmaxf(acc[i][j][1] + b1, 0.0f)) << 16)
                     | ((u64)f2b(fmaxf(acc[i][j][2] + b2v, 0.0f)) << 32)
                     | ((u64)f2b(fmaxf(acc[i][j][3] + b3, 0.0f)) << 48);
            *(u64*)&Out[(size_t)(roi * 196 + col) * 256 + m] = pack;
        }
    }
}

// ---------------- bf16 MFMA deconv: M=1024 (o*4+d), K=256, out f32 NCHW 28x28 ----------------
// R15: staging converted to global_load_lds (linear dest, inverse-swizzled
// source, same granule involution g^((g>>3)&3) as gemm3/conv — read side
// untouched) + double-buffered across the 8 K-steps (prologue + prefetch
// next step during compute). Removes the global->VGPR->ds_write round trip
// and the fully-exposed per-step drain. OOB B-columns (col >= NC) now read
// in-workspace garbage instead of zeros — safe: MFMA output columns are
// independent, and cols >= NC are never stored (same argument as R6).
// Operand values and MFMA order unchanged -> bitwise-identical.
__global__ __launch_bounds__(256) void deconv_mfma_k(const ushort_t* __restrict__ Wb,
        const ushort_t* __restrict__ In, const float* __restrict__ bias,
        float* __restrict__ Out, int NC) {
    __shared__ __align__(16) ushort_t As[2][2048];
    __shared__ __align__(16) ushort_t Bs[2][2048];
    int t = threadIdx.x;
    int wave = t >> 6, lane = t & 63;
    int wm = wave >> 1, wn = wave & 1;
    int m0 = blockIdx.y * 64, n0 = blockIdx.x * 64;
    f4v acc[2][2] = {};
    int rl = lane & 15, kseg = lane >> 4;
    // linear LDS dest granule t holds logical granule L = t^((t>>3)&3);
    // decode L -> (row, kseg) for A and (col, kseg) for B.
    int gsw = t ^ ((t >> 3) & 3);
    const ushort_t* asrc = Wb + (size_t)(m0 + (gsw >> 2)) * 256 + (gsw & 3) * 8;
    const ushort_t* bsrc = In + (size_t)(n0 + (gsw >> 2)) * 256 + (gsw & 3) * 8;
    // prologue: stage k0=0 into buf 0
    gload16(&asrc[0], &As[0][t * 8]);
    gload16(&bsrc[0], &Bs[0][t * 8]);
    __syncthreads();
    int cur = 0;
    for (int k0 = 0; k0 < 256; k0 += 32) {
        if (k0 + 32 < 256) {
            gload16(&asrc[k0 + 32], &As[cur ^ 1][t * 8]);
            gload16(&bsrc[k0 + 32], &Bs[cur ^ 1][t * 8]);
        }
        s8v a[2], b[2];
#pragma unroll
        for (int i = 0; i < 2; i++) {
            int row = wm * 32 + i * 16 + rl;
            int idx = row * 32 + kseg * 8;
            idx ^= ((idx >> 6) & 3) << 3;
            a[i] = *(const s8v*)&As[cur][idx];
        }
#pragma unroll
        for (int j = 0; j < 2; j++) {
            int col = wn * 32 + j * 16 + rl;
            int idx = col * 32 + kseg * 8;
            idx ^= ((idx >> 6) & 3) << 3;
            b[j] = *(const s8v*)&Bs[cur][idx];
        }
#pragma unroll
        for (int i = 0; i < 2; i++)
#pragma unroll
            for (int j = 0; j < 2; j++)
                acc[i][j] = MFMA16(a[i], b[j], acc[i][j]);
        __syncthreads();
        cur ^= 1;
    }
    int rq = lane >> 4;
#pragma unroll
    for (int i = 0; i < 2; i++) {
#pragma unroll
        for (int j = 0; j < 2; j++) {
            int col = n0 + wn * 32 + j * 16 + rl;
            if (col >= NC) continue;
            int n = col / 196;
            int p = col - n * 196;
            int y = p / 14, x = p - y * 14;
            int m = m0 + wm * 32 + i * 16 + rq * 4;
            int o = m >> 2;
            float bv = bias[o];
            float2 lo, hi;
            lo.x = fmaxf(acc[i][j][0] + bv, 0.0f);
            lo.y = fmaxf(acc[i][j][1] + bv, 0.0f);
            hi.x = fmaxf(acc[i][j][2] + bv, 0.0f);
            hi.y = fmaxf(acc[i][j][3] + bv, 0.0f);
            size_t base = ((size_t)n * 256 + o) * 784;
            *(float2*)&Out[base + (size_t)(2 * y) * 28 + 2 * x] = lo;
            *(float2*)&Out[base + (size_t)(2 * y + 1) * 28 + 2 * x] = hi;
        }
    }
}

// ---------------- softmax over 81 + box decode for classes 1..80 ----------------
__global__ __launch_bounds__(128) void softmax_decode_k(const float* __restrict__ logits,
        const float* __restrict__ reg, const float* __restrict__ bbox,
        float* __restrict__ scores_c, float* __restrict__ boxes_c) {
    int n = blockIdx.x, t = threadIdx.x;
    __shared__ float sl[81];
    __shared__ float red[128];
    if (t < 81) sl[t] = logits[n * 81 + t];
    __syncthreads();
    red[t] = (t < 81) ? sl[t] : -3.0e38f;
    __syncthreads();
    for (int s = 64; s > 0; s >>= 1) { if (t < s) red[t] = fmaxf(red[t], red[t + s]); __syncthreads(); }
    float mx = red[0];
    __syncthreads();
    float e = (t < 81) ? expf(sl[t] - mx) : 0.0f;
    red[t] = e;
    __syncthreads();
    for (int s = 64; s > 0; s >>= 1) { if (t < s) red[t] += red[t + s]; __syncthreads(); }
    float sum = red[0];
    if (t >= 1 && t < 81) {
        float score = e / sum;
        float bx1 = bbox[n * 4 + 0], by1 = bbox[n * 4 + 1];
        float bx2 = bbox[n * 4 + 2], by2 = bbox[n * 4 + 3];
        float w = bx2 - bx1 + 1.0f, h = by2 - by1 + 1.0f;
        float cx = bx1 + 0.5f * w, cy = by1 + 0.5f * h;
        const float* dn = reg + (size_t)n * 324 + t * 4;
        float dx = dn[0] / 10.0f;
        float dy = dn[1] / 10.0f;
        float dw = fminf(dn[2] / 5.0f, CLAMPV);
        float dh = fminf(dn[3] / 5.0f, CLAMPV);
        float pcx = dx * w + cx, pcy = dy * h + cy;
        float pw = expf(dw) * w, ph = expf(dh) * h;
        float x1 = fminf(fmaxf(pcx - 0.5f * pw, 0.0f), 799.0f);
        float y1 = fminf(fmaxf(pcy - 0.5f * ph, 0.0f), 799.0f);
        float x2 = fminf(fmaxf(pcx + 0.5f * pw - 1.0f, 0.0f), 799.0f);
        float y2 = fminf(fmaxf(pcy + 0.5f * ph - 1.0f, 0.0f), 799.0f);
        int cc = t - 1;
        scores_c[cc * 512 + n] = score;
        float* bo = boxes_c + ((size_t)cc * 512 + n) * 4;
        bo[0] = x1; bo[1] = y1; bo[2] = x2; bo[3] = y2;
    }
}

// ---------------- per-class NMS, score-filtered; compact candidate append ----------------
__global__ __launch_bounds__(256) void nms_k(const float* __restrict__ scores_c,
        const float* __restrict__ boxes_c, u64* __restrict__ cand, int* __restrict__ cnt) {
    int c = blockIdx.x, t = threadIdx.x;
    int lane = t & 63, wave = t >> 6;
    __shared__ float s[512];
    __shared__ float fs[512];
    __shared__ short fidx[512];
    __shared__ float4 ob[512];
    __shared__ short sidx[512];
    __shared__ u64 mask[512][8];
    __shared__ u64 remw[8];
    __shared__ unsigned char stat[512];
    __shared__ int mcnt;
    if (t == 0) mcnt = 0;
    for (int i = t; i < 512; i += 256) {
        s[i] = scores_c[c * 512 + i];
        stat[i] = 0;
    }
    __syncthreads();
    for (int i = t; i < 512; i += 256) {
        if (s[i] > SCORE_THR) {
            int p = atomicAdd(&mcnt, 1);
            fs[p] = s[i];
            fidx[p] = (short)i;
        }
    }
    __syncthreads();
    int m = mcnt;
    if (m > 0) {
        for (int i = t; i < m; i += 256) {
            float si = fs[i];
            int ii = fidx[i];
            int r = 0;
            for (int j = 0; j < m; j++) {
                float sj = fs[j];
                r += (sj > si) || (sj == si && fidx[j] < ii);
            }
            sidx[r] = (short)ii;
        }
        __syncthreads();
        for (int r = t; r < m; r += 256)
            ob[r] = *(const float4*)(boxes_c + ((size_t)c * 512 + sidx[r]) * 4);
        __syncthreads();
        int W = (m + 63) >> 6;
        for (int i = wave; i < m; i += 4) {
            float4 a = ob[i];
            float aarea = (a.z - a.x + 1.0f) * (a.w - a.y + 1.0f);
            for (int b = 0; b < W; b++) {
                int j = b * 64 + lane;
                float4 bb = ob[j < m ? j : 0];
                float barea = (bb.z - bb.x + 1.0f) * (bb.w - bb.y + 1.0f);
                float lx = fmaxf(a.x, bb.x), lyv = fmaxf(a.y, bb.y);
                float rx = fminf(a.z, bb.z), ry = fminf(a.w, bb.w);
                float iw = fmaxf(rx - lx + 1.0f, 0.0f);
                float ih = fmaxf(ry - lyv + 1.0f, 0.0f);
                float inter = iw * ih;
                float iou = inter / (aarea + barea - inter);
                u64 bal = __ballot((j < m) && (j > i) && (iou > NMS_THR));
                if (lane == 0) mask[i][b] = bal;
            }
        }
        __syncthreads();
        if (wave == 0) {
            u64 rm = 0;
            for (int i = 0; i < m; i++) {
                u64 w = shfl64(rm, i >> 6);
                if (!((w >> (i & 63)) & 1ull) && lane < W) rm |= mask[i][lane];
            }
            if (lane < 8) remw[lane] = rm;
        }
        __syncthreads();
        for (int r = t; r < m; r += 256) {
            bool kept = !((remw[r >> 6] >> (r & 63)) & 1ull);
            if (kept) stat[sidx[r]] = 1;
        }
        __syncthreads();
    }
    // append: all positives, plus class-0 flats 0..199 as the -1.0 pad pool.
    for (int i = t; i < 512; i += 256) {
        float val = stat[i] ? s[i] : -1.0f;
        if ((c == 0 && i < 200) || val != -1.0f) {
            int flat = c * 512 + i;
            u32 u = __float_as_uint(val);
            u = (u & 0x80000000u) ? ~u : (u | 0x80000000u);
            u64 key = ((u64)u << 32) | (u64)(0xFFFFFFFFu - (u32)flat);
            int pos = atomicAdd(cnt, 1);
            cand[pos] = key;
        }
    }
}

// ---------------- top-100 via parallel rank selection (keys strictly unique) ----------------
#define TCAP 8192
#define TCHUNK (TCAP - 128)
__global__ __launch_bounds__(512) void topk3_k(const u64* __restrict__ cand,
        const int* __restrict__ cnt, const float* __restrict__ boxes_c,
        float* __restrict__ out) {
    __shared__ u64 ck[TCAP];
    __shared__ u64 wk[100];
    int t = threadIdx.x;
    int n = *cnt;
    for (int i = t; i < 100; i += 512) wk[i] = 0;
    __syncthreads();
    for (int base = 0; base < n; base += TCHUNK) {
        int sz = min(n - base, TCHUNK);
        for (int i = t; i < 100; i += 512) ck[i] = wk[i];
        for (int i = t; i < sz; i += 512) ck[100 + i] = cand[base + i];
        int tot = 100 + sz;
        __syncthreads();
        for (int i = t; i < tot; i += 512) {
            u64 ki = ck[i];
            int r = 0;
            for (int j = 0; j < tot; j++) {
                u64 kj = ck[j];
                r += (kj > ki) || (kj == ki && j < i);
                if (r >= 100) break;
            }
            if (r < 100) wk[r] = ki;
        }
        __syncthreads();
    }
    if (t < 100) {
        u64 bk = wk[t];
        u32 flat = 0xFFFFFFFFu - (u32)(bk & 0xFFFFFFFFull);
        u32 u = (u32)(bk >> 32);
        float val = (u & 0x80000000u) ? __uint_as_float(u & 0x7FFFFFFFu)
                                      : __uint_as_float(~u);
        int cls = (int)(flat >> 9);
        out[t * 4 + 0] = boxes_c[(size_t)flat * 4 + 0];
        out[t * 4 + 1] = boxes_c[(size_t)flat * 4 + 1];
        out[t * 4 + 2] = boxes_c[(size_t)flat * 4 + 2];
        out[t * 4 + 3] = boxes_c[(size_t)flat * 4 + 3];
        out[400 + t] = (float)(cls + 1);
        out[78900 + t] = fmaxf(val, 0.0f);
    }
}

// ---------------- mask head stage 1: partial dot over 32 channels ----------------
__global__ __launch_bounds__(256) void mask_part_k(const float* __restrict__ D,
        const float* __restrict__ w2, const float* __restrict__ out,
        float* __restrict__ MP) {
    int n = blockIdx.x, q = blockIdx.y, t = threadIdx.x;
    int lab = (int)(out[400 + n] + 0.5f);
    __shared__ float wsh[32];
    if (t < 32) wsh[t] = w2[lab * 256 + q * 32 + t];
    __syncthreads();
    const float* Dn = D + (size_t)n * 256 * 784 + (size_t)q * 32 * 784;
    float a0 = 0.0f, a1 = 0.0f, a2 = 0.0f, a3 = 0.0f;
    for (int o = 0; o < 32; o++) {
        float wv = wsh[o];
        const float* Dp = Dn + o * 784;
        a0 += Dp[t] * wv;
        a1 += Dp[t + 256] * wv;
        a2 += Dp[t + 512] * wv;
        if (t < 16) a3 += Dp[t + 768] * wv;
    }
    float* mp = MP + ((size_t)n * 8 + q) * 784;
    mp[t] = a0;
    mp[t + 256] = a1;
    mp[t + 512] = a2;
    if (t < 16) mp[t + 768] = a3;
}

// ---------------- mask head stage 2: sum 8 partials + bias + sigmoid ----------------
__global__ __launch_bounds__(256) void mask_fin_k(const float* __restrict__ MP,
        const float* __restrict__ b2, float* __restrict__ out) {
    int n = blockIdx.x, t = threadIdx.x;
    int lab = (int)(out[400 + n] + 0.5f);
    float bb = b2[lab];
    const float* mp = MP + (size_t)n * 8 * 784;
    for (int p = t; p < 784; p += 256) {
        float s = 0.0f;
#pragma unroll
        for (int q = 0; q < 8; q++) s += mp[q * 784 + p];
        s += bb;
        out[500 + n * 784 + p] = 1.0f / (1.0f + expf(-s));
    }
}

extern "C" void kernel_launch(void* const* d_in, const int* in_sizes, int n_in,
                              void* d_out, int out_size, void* d_ws, size_t ws_size,
                              hipStream_t stream) {
    const float* features = (const float*)d_in[0];
    const float* bbox = (const float*)d_in[1];
    const float* fc1_w = (const float*)d_in[3];
    const float* fc1_b = (const float*)d_in[4];
    const float* fc2_w = (const float*)d_in[5];
    const float* fc2_b = (const float*)d_in[6];
    const float* cls_w = (const float*)d_in[7];
    const float* cls_b = (const float*)d_in[8];
    const float* reg_w = (const float*)d_in[9];
    const float* reg_b = (const float*)d_in[10];
    const float* mc1w = (const float*)d_in[11];
    const float* mc1b = (const float*)d_in[12];
    const float* mc2w = (const float*)d_in[13];
    const float* mc2b = (const float*)d_in[14];
    const float* mc3w = (const float*)d_in[15];
    const float* mc3b = (const float*)d_in[16];
    const float* mc4w = (const float*)d_in[17];
    const float* mc4b = (const float*)d_in[18];
    const float* dcw = (const float*)d_in[19];
    const float* dcb = (const float*)d_in[20];
    const float* mpw = (const float*)d_in[21];
    const float* mpb = (const float*)d_in[22];
    float* out = (float*)d_out;
    float* ws = (float*)d_ws;

    // ---- workspace layout (float offsets), time-multiplexed ----
    // GEMM partials live at [20,070,400 .. 24,264,704) — dead during the
    // detect phase (Abf/Bbf are mask-phase-only, W1b+ start at 25.09M,
    // CAND/CNT end below 19.68M). FEAT at ws+0 survives until
    // roi_align_mask_k -> no second transpose. D overlays ws+0 afterward.
    float* FEAT = ws + 0;
    float* D    = ws + 0;                         // mask phase (deconv out)
    ushort_t* XFh = (ushort_t*)(ws + 10240000);
    ushort_t* XFl = (ushort_t*)(ws + 13451264);
    ushort_t* W1h = (ushort_t*)(ws + 16662528);
    ushort_t* W1l = (ushort_t*)(ws + 23085056);   // [.. 29,507,584)
    ushort_t* H1h = (ushort_t*)(ws + 16662528);
    ushort_t* H1l = (ushort_t*)(ws + 16924672);
    ushort_t* H2h = (ushort_t*)(ws + 17186816);
    ushort_t* H2l = (ushort_t*)(ws + 17448960);
    ushort_t* W2h = (ushort_t*)(ws + 17711104);
    ushort_t* W2l = (ushort_t*)(ws + 18235392);
    ushort_t* Wcrh = (ushort_t*)(ws + 18759680);
    ushort_t* Wcrl = (ushort_t*)(ws + 18967040);
    float* LOGI = ws + 19174400;
    float* REG  = ws + 19215872;
    float* BXC  = ws + 19381760;
    float* SCC  = ws + 19545600;
    u64*  CAND  = (u64*)(ws + 19586560);
    int*  CNT   = (int*)(ws + 19670000);
    float* PARTg = ws + 20070400;                 // detect phase, 4.19M floats
    ushort_t* Abf = (ushort_t*)(ws + 20070400);   // mask phase (over dead PART)
    ushort_t* Bbf = (ushort_t*)(ws + 22579200);
    ushort_t* W1b = (ushort_t*)(ws + 25088000);
    ushort_t* W2b = (ushort_t*)(ws + 25382912);
    ushort_t* W3b = (ushort_t*)(ws + 25677824);
    ushort_t* W4b = (ushort_t*)(ws + 25972736);
    ushort_t* WDb = (ushort_t*)(ws + 26267648);   // ends 26,398,720
    float* MP   = ws + 26398720;

    transpose_k<<<dim3(1250, 8), dim3(32, 8), 0, stream>>>(features, FEAT, 256, 40000);
    cvt_w1_k<<<1024, 256, 0, stream>>>(fc1_w, W1h, W1l);
    roi_align_hilo_k<<<dim3(49, 512), 256, 0, stream>>>(FEAT, bbox, XFh, XFl);

    // fc1: 128x128-tile K-blocked double-buffered kernel, XCD-aware grid:
    // launched (z, x, y) so the K-chunk is the fastest dim -> one XCD per chunk.
    gemm128_k<<<dim3(8, 8, 4), 512, 0, stream>>>(XFh, XFl, W1h, W1l, PARTg, 512, 1024, 392, 49);
    reduce2_k<<<2048, 256, 0, stream>>>(PARTg, fc1_b, (float*)nullptr, H1h, H1l, 512, 1024, 8, 1);

    cvt_hilo3_k<<<5716, 256, 0, stream>>>(fc2_w, cls_w, reg_w, W2h, W2l,
            Wcrh, Wcrl, Wcrh + 81 * 1024, Wcrl + 81 * 1024);
    cvt_allw_k<<<10240, 256, 0, stream>>>(mc1w, mc2w, mc3w, mc4w, dcw, W1b, W2b, W3b, W4b, WDb, CNT);

    gemm3_mfma_k<<<dim3(16, 8, 8), 256, 0, stream>>>(H1h, H1l, W2h, W2l, PARTg, 512, 1024, 1024, 128);
    reduce2_k<<<2048, 256, 0, stream>>>(PARTg, fc2_b, (float*)nullptr, H2h, H2l, 512, 1024, 8, 1);
    gemm3_mfma_k<<<dim3(7, 8, 8), 256, 0, stream>>>(H2h, H2l, Wcrh, Wcrl, PARTg, 512, 405, 1024, 128);
    reduce_cr_k<<<810, 256, 0, stream>>>(PARTg, cls_b, reg_b, LOGI, REG);
    // PARTg dead from here.

    softmax_decode_k<<<512, 128, 0, stream>>>(LOGI, REG, bbox, SCC, BXC);
    nms_k<<<80, 256, 0, stream>>>(SCC, BXC, CAND, CNT);
    topk3_k<<<1, 512, 0, stream>>>(CAND, CNT, BXC, out);

    // mask branch: FEAT still intact (no second transpose needed)
    roi_align_mask_k<<<dim3(196, 100), 256, 0, stream>>>(FEAT, out, Abf);
    conv3_roi_k<<<416, 256, 0, stream>>>(W1b, Abf, mc1b, Bbf);
    conv3_roi_k<<<416, 256, 0, stream>>>(W2b, Bbf, mc2b, Abf);
    conv3_roi_k<<<416, 256, 0, stream>>>(W3b, Abf, mc3b, Bbf);
    conv3_roi_k<<<416, 256, 0, stream>>>(W4b, Bbf, mc4b, Abf);
    deconv_mfma_k<<<dim3(307, 16), 256, 0, stream>>>(WDb, Abf, dcb, D, 19600);
    mask_part_k<<<dim3(100, 8), 256, 0, stream>>>(D, mpw, out, MP);
    mask_fin_k<<<100, 256, 0, stream>>>(MP, mpb, out);
}